// Round 3
// baseline (707.721 us; speedup 1.0000x reference)
//
#include <hip/hip_runtime.h>
#include <hip/hip_bf16.h>

typedef __bf16 bf16_t;
typedef __attribute__((ext_vector_type(8))) __bf16 bf16x8;
typedef __attribute__((ext_vector_type(4))) __bf16 bf16x4;
typedef __attribute__((ext_vector_type(4))) float f32x4;

#define D_IN   2048
#define D_SAE  16384
#define NROWS  4096
#define NFEAT  4096     // INIT_FEATURES (first NFEAT features unmasked; rest exactly zero)
#define TOPK   1638
#define W_EPS  1e-8f
#define LN_EPS 1e-5f
#define TEMP_INV 10.0f

// ---------------- reductions ----------------
__device__ inline float blockSumF(float v, float* red) {
#pragma unroll
  for (int o = 32; o; o >>= 1) v += __shfl_xor(v, o, 64);
  __syncthreads();
  if ((threadIdx.x & 63) == 0) red[threadIdx.x >> 6] = v;
  __syncthreads();
  return red[0] + red[1] + red[2] + red[3];
}

__device__ inline int blockSumI(int v, int* red) {
#pragma unroll
  for (int o = 32; o; o >>= 1) v += __shfl_xor(v, o, 64);
  __syncthreads();
  if ((threadIdx.x & 63) == 0) red[threadIdx.x >> 6] = v;
  __syncthreads();
  return red[0] + red[1] + red[2] + red[3];
}

// ---------------- W_enc column norms ----------------
__global__ __launch_bounds__(256) void col_norm_partial(const float* __restrict__ W,
                                                        float* __restrict__ part) {
  int col = blockIdx.x * 256 + threadIdx.x;   // 0..16383
  int rc = blockIdx.y;                        // 0..7
  const float* p = W + (size_t)rc * 256 * D_SAE + col;
  float s = 0.f;
#pragma unroll 8
  for (int r = 0; r < 256; ++r) {
    float v = p[(size_t)r * D_SAE];
    s += v * v;
  }
  part[(size_t)rc * D_SAE + col] = s;
}

__global__ __launch_bounds__(256) void col_norm_finalize(const float* __restrict__ part,
                                                         float* __restrict__ scale) {
  int col = blockIdx.x * 256 + threadIdx.x;
  float s = 0.f;
#pragma unroll
  for (int c = 0; c < 8; ++c) s += part[(size_t)c * D_SAE + col];
  scale[col] = 1.0f / (sqrtf(s) + W_EPS);
}

// ---------------- W_dec row norms (rows 0..NFEAT-1), one wave per row ----------------
__global__ __launch_bounds__(256) void row_norm_kernel(const float* __restrict__ W,
                                                       float* __restrict__ scale) {
  int gw = (blockIdx.x * 256 + threadIdx.x) >> 6;  // row
  int lane = threadIdx.x & 63;
  const float4* r4 = (const float4*)(W + (size_t)gw * D_IN);
  float s = 0.f;
#pragma unroll
  for (int i = 0; i < (D_IN / 4) / 64; ++i) {  // 8 iters
    float4 v = r4[lane + i * 64];
    s += v.x * v.x + v.y * v.y + v.z * v.z + v.w * v.w;
  }
#pragma unroll
  for (int o = 32; o; o >>= 1) s += __shfl_xor(s, o, 64);
  if (lane == 0) scale[gw] = 1.0f / (sqrtf(s) + W_EPS);
}

// ---------------- transpose + scale + cast to bf16 ----------------
template <int SCALE_AXIS>
__global__ __launch_bounds__(256) void transpose_scale_cast(
    const float* __restrict__ in, const float* __restrict__ scale,
    bf16_t* __restrict__ out, int C, int Rout) {
  __shared__ float t[64][65];
  int c0 = blockIdx.x * 64;
  int r0 = blockIdx.y * 64;
  int tx = threadIdx.x & 63;
  int ty = threadIdx.x >> 6;
#pragma unroll
  for (int i = 0; i < 16; ++i) {
    int r = ty * 16 + i;
    float v = in[(size_t)(r0 + r) * C + (c0 + tx)];
    float sc = (SCALE_AXIS == 0) ? scale[c0 + tx] : scale[r0 + r];
    t[r][tx] = v * sc;
  }
  __syncthreads();
#pragma unroll
  for (int i = 0; i < 16; ++i) {
    int r = ty * 16 + i;
    out[(size_t)(c0 + r) * Rout + (r0 + tx)] = (bf16_t)t[tx][r];
  }
}

// ---------------- cast acts f32 -> bf16 ----------------
__global__ __launch_bounds__(256) void cast_bf16_kernel(const float* __restrict__ in,
                                                        bf16_t* __restrict__ out, int n4) {
  int i = blockIdx.x * 256 + threadIdx.x;
  if (i < n4) {
    float4 v = ((const float4*)in)[i];
    bf16x4 o;
    o[0] = (bf16_t)v.x; o[1] = (bf16_t)v.y; o[2] = (bf16_t)v.z; o[3] = (bf16_t)v.w;
    *(bf16x4*)(out + (size_t)i * 4) = o;
  }
}

__device__ inline void gload_lds16(const bf16_t* g, bf16_t* l) {
  __builtin_amdgcn_global_load_lds((__attribute__((address_space(1))) void*)g,
                                   (__attribute__((address_space(3))) void*)l,
                                   16, 0, 0);
}

// ============ 256x256 deep-pipelined bf16 MFMA GEMM (counted vmcnt) ============
// C[M][N] = A[M][K](bf16,row-major) * BT[N][K]^T (bf16,row-major) + bias[N]
// Requires: M%256==0, N%256==0, K%64==0, K/64 >= 2.
__global__ __launch_bounds__(512, 2) void gemm256(
    const bf16_t* __restrict__ A, const bf16_t* __restrict__ BT,
    const float* __restrict__ bias, float* __restrict__ C,
    int N, int K, int lda, int ldb) {
  __shared__ __align__(16) bf16_t As[2][256 * 64];
  __shared__ __align__(16) bf16_t Bs[2][256 * 64];

  const int tid = threadIdx.x;
  const int lane = tid & 63;
  const int w = tid >> 6;       // 0..7
  const int wm = w >> 2;        // 0..1  (row half)
  const int wn = w & 3;         // 0..3  (col quarter)

  // XCD swizzle: each XCD owns a contiguous range of column stripes.
  const int gx = gridDim.x, gy = gridDim.y;
  const int nwg = gx * gy;
  int orig = blockIdx.y * gx + blockIdx.x;
  int wgid = orig;
  if ((nwg & 7) == 0) wgid = (orig & 7) * (nwg >> 3) + (orig >> 3);
  const int bx = wgid / gy;       // N-tile (column-major decomposition)
  const int by = wgid % gy;       // M-tile
  const long brow = (long)by * 256;
  const long bcol = (long)bx * 256;

  // ---- staging addresses (pre-swizzled global source; linear LDS dest) ----
  const int srow = lane >> 3;                       // 0..7
  const int sgran = ((lane & 7) ^ srow) * 8;        // logical k-offset (elems)
  const bf16_t* ap = A + (size_t)(brow + w * 8 + srow) * lda + sgran;
  const bf16_t* bp = BT + (size_t)(bcol + w * 8 + srow) * ldb + sgran;
  const int ldsw = w * 1024;                        // byte offset, wave-uniform

#define STAGE_TILE(p_)                                                        \
  do {                                                                        \
    char* ab = (char*)&As[p_][0] + ldsw;                                      \
    char* bb = (char*)&Bs[p_][0] + ldsw;                                      \
    gload_lds16(ap, (bf16_t*)(ab));                                           \
    gload_lds16(ap + (size_t)64 * lda, (bf16_t*)(ab + 8192));                 \
    gload_lds16(ap + (size_t)128 * lda, (bf16_t*)(ab + 16384));               \
    gload_lds16(ap + (size_t)192 * lda, (bf16_t*)(ab + 24576));               \
    gload_lds16(bp, (bf16_t*)(bb));                                           \
    gload_lds16(bp + (size_t)64 * ldb, (bf16_t*)(bb + 8192));                 \
    gload_lds16(bp + (size_t)128 * ldb, (bf16_t*)(bb + 16384));               \
    gload_lds16(bp + (size_t)192 * ldb, (bf16_t*)(bb + 24576));               \
    ap += 64; bp += 64;                                                       \
  } while (0)

  // ---- fragment read addressing (swizzled) ----
  const int fr = lane & 15;
  const int kq16 = (lane >> 4) * 16;                // byte offset of k-quarter
  const int xr = (fr & 7) << 4;                     // swizzle XOR
  const int arow = (wm * 128 + fr) * 128;           // byte row base within A tile
  const int brow_b = (wn * 64 + fr) * 128;          // byte row base within B tile

  f32x4 acc[8][4] = {};

  const int NT = K >> 6;
  // prologue: tiles 0 and 1
  STAGE_TILE(0);
  STAGE_TILE(1);

  for (int t = 0; t < NT; ++t) {
    const int p = t & 1;
    if (t < NT - 1) {
      asm volatile("s_waitcnt vmcnt(8)" ::: "memory");
    } else {
      asm volatile("s_waitcnt vmcnt(0)" ::: "memory");
    }
    __builtin_amdgcn_sched_barrier(0);
    __builtin_amdgcn_s_barrier();          // all waves' loads for tile t landed
    __builtin_amdgcn_sched_barrier(0);

    const char* aB = (const char*)&As[p][0] + arow;
    const char* bB = (const char*)&Bs[p][0] + brow_b;

    bf16x8 bfr[4][2];
#pragma unroll
    for (int n = 0; n < 4; ++n) {
      bfr[n][0] = *(const bf16x8*)(bB + n * 2048 + (kq16 ^ xr));
      bfr[n][1] = *(const bf16x8*)(bB + n * 2048 + ((kq16 + 64) ^ xr));
    }
    __builtin_amdgcn_s_setprio(1);
#pragma unroll
    for (int m = 0; m < 8; ++m) {
      bf16x8 a0 = *(const bf16x8*)(aB + m * 2048 + (kq16 ^ xr));
      bf16x8 a1 = *(const bf16x8*)(aB + m * 2048 + ((kq16 + 64) ^ xr));
#pragma unroll
      for (int n = 0; n < 4; ++n) {
        acc[m][n] = __builtin_amdgcn_mfma_f32_16x16x32_bf16(a0, bfr[n][0], acc[m][n], 0, 0, 0);
        acc[m][n] = __builtin_amdgcn_mfma_f32_16x16x32_bf16(a1, bfr[n][1], acc[m][n], 0, 0, 0);
      }
    }
    __builtin_amdgcn_s_setprio(0);

    __builtin_amdgcn_sched_barrier(0);
    __builtin_amdgcn_s_barrier();          // all waves done reading buf p
    __builtin_amdgcn_sched_barrier(0);
    if (t + 2 < NT) {
      STAGE_TILE(p);                       // overwrite freed buffer with tile t+2
    }
  }
#undef STAGE_TILE

  // ---- epilogue ----
  float bval[4];
#pragma unroll
  for (int n = 0; n < 4; ++n) bval[n] = bias[bcol + wn * 64 + n * 16 + fr];
#pragma unroll
  for (int m = 0; m < 8; ++m) {
#pragma unroll
    for (int r = 0; r < 4; ++r) {
      size_t row = brow + wm * 128 + m * 16 + (lane >> 4) * 4 + r;
      float* cp = C + row * (size_t)N + bcol + wn * 64 + fr;
#pragma unroll
      for (int n = 0; n < 4; ++n) cp[n * 16] = acc[m][n][r] + bval[n];
    }
  }
}

// ---------------- unified 128x128 MFMA GEMM (fallback / GEMM2) ----------------
template <int AMODE, int BMODE>
__global__ __launch_bounds__(256, 2) void gemm_tile(
    const void* __restrict__ Ap, const void* __restrict__ Bp,
    const float* __restrict__ bscale, const float* __restrict__ bias,
    float* __restrict__ C, int N, int K, int lda, int ldb) {
  __shared__ __align__(16) bf16_t As[128 * 32];
  __shared__ __align__(16) bf16_t Bs[128 * 32];
  const int tid = threadIdx.x;
  const int lane = tid & 63;
  const int wid = tid >> 6;
  const int wm = wid >> 1, wn = wid & 1;
  const long brow = (long)blockIdx.y * 128;
  const long bcol = (long)blockIdx.x * 128;

  f32x4 acc[4][4] = {};

  const bf16_t* ag = nullptr; bf16_t* al = nullptr;
  const float* af32 = nullptr;
  if (AMODE == 0) {
    ag = (const bf16_t*)Ap + (size_t)(brow + wid * 32 + (lane >> 2)) * lda + (lane & 3) * 8;
    al = &As[(wid * 32) * 32];
  } else {
    af32 = (const float*)Ap;
  }
  const bf16_t* bg = nullptr; bf16_t* bl = nullptr;
  const float* bf32 = nullptr;
  if (BMODE == 0) {
    bg = (const bf16_t*)Bp + (size_t)(bcol + wid * 32 + (lane >> 2)) * ldb + (lane & 3) * 8;
    bl = &Bs[(wid * 32) * 32];
  } else {
    bf32 = (const float*)Bp;
  }

  const int fr = lane & 15;
  const int kc = (lane >> 4) * 8;
  const int aoff0 = (wm * 64 + fr) * 32 + kc;
  const int boff0 = (wn * 64 + fr) * 32 + kc;

  for (int kt = 0; kt < K; kt += 32) {
    if (AMODE == 0) {
      gload_lds16(ag + kt, al);
      gload_lds16(ag + kt + (size_t)16 * lda, al + 16 * 32);
    } else {
#pragma unroll
      for (int i = 0; i < 4; ++i) {
        int flat = tid + i * 256;
        int r = flat >> 3;
        int k4 = flat & 7;
        float4 v = *(const float4*)&af32[(size_t)(brow + r) * lda + kt + k4 * 4];
        bf16x4 o;
        o[0] = (bf16_t)v.x; o[1] = (bf16_t)v.y; o[2] = (bf16_t)v.z; o[3] = (bf16_t)v.w;
        *(bf16x4*)&As[r * 32 + k4 * 4] = o;
      }
    }
    if (BMODE == 0) {
      gload_lds16(bg + kt, bl);
      gload_lds16(bg + kt + (size_t)16 * ldb, bl + 16 * 32);
    } else {
#pragma unroll
      for (int i = 0; i < 4; ++i) {
        int flat = tid + i * 256;
        int k = flat >> 5;
        int c4 = flat & 31;
        float4 v = *(const float4*)&bf32[(size_t)(kt + k) * ldb + bcol + c4 * 4];
        float4 sc;
        if (BMODE == 1) {
          sc = *(const float4*)&bscale[bcol + c4 * 4];
        } else {
          float s = bscale[kt + k];
          sc.x = s; sc.y = s; sc.z = s; sc.w = s;
        }
        Bs[(c4 * 4 + 0) * 32 + k] = (bf16_t)(v.x * sc.x);
        Bs[(c4 * 4 + 1) * 32 + k] = (bf16_t)(v.y * sc.y);
        Bs[(c4 * 4 + 2) * 32 + k] = (bf16_t)(v.z * sc.z);
        Bs[(c4 * 4 + 3) * 32 + k] = (bf16_t)(v.w * sc.w);
      }
    }
    __syncthreads();
    bf16x8 afr[4], bfr[4];
#pragma unroll
    for (int m = 0; m < 4; ++m) afr[m] = *(const bf16x8*)&As[aoff0 + m * 16 * 32];
#pragma unroll
    for (int n = 0; n < 4; ++n) bfr[n] = *(const bf16x8*)&Bs[boff0 + n * 16 * 32];
#pragma unroll
    for (int m = 0; m < 4; ++m)
#pragma unroll
      for (int n = 0; n < 4; ++n)
        acc[m][n] = __builtin_amdgcn_mfma_f32_16x16x32_bf16(afr[m], bfr[n], acc[m][n], 0, 0, 0);
    __syncthreads();
  }

  float bval[4];
#pragma unroll
  for (int n = 0; n < 4; ++n) bval[n] = bias[bcol + wn * 64 + n * 16 + fr];
#pragma unroll
  for (int m = 0; m < 4; ++m) {
#pragma unroll
    for (int r = 0; r < 4; ++r) {
      size_t row = brow + wm * 64 + m * 16 + (lane >> 4) * 4 + r;
      float* cp = C + row * (size_t)N + bcol + wn * 64 + fr;
#pragma unroll
      for (int n = 0; n < 4; ++n) cp[n * 16] = acc[m][n][r] + bval[n];
    }
  }
}

// ---------------- per-row: LN -> affine -> LN -> exact topK thr -> encoded ----------------
__global__ __launch_bounds__(256) void row_process(
    const float* __restrict__ pre, const float* __restrict__ ln_w,
    const float* __restrict__ ln_b, const float* __restrict__ fmask,
    bf16_t* __restrict__ enc_base) {
  __shared__ float redf[4];
  __shared__ int redi[4];
  const int tid = threadIdx.x;
  const size_t row = blockIdx.x;
  const float4* xr = (const float4*)(pre + row * D_SAE);

  float4 x[16];
  float s = 0.f, s2 = 0.f;
#pragma unroll
  for (int j = 0; j < 16; ++j) {
    float4 v = xr[tid + j * 256];
    x[j] = v;
    s += v.x + v.y + v.z + v.w;
    s2 += v.x * v.x + v.y * v.y + v.z * v.z + v.w * v.w;
  }
  float S1 = blockSumF(s, redf);
  float S2 = blockSumF(s2, redf);
  float mu = S1 * (1.0f / D_SAE);
  float var = S2 * (1.0f / D_SAE) - mu * mu;
  float inv = rsqrtf(var + LN_EPS);

  const float4* wr = (const float4*)ln_w;
  const float4* br = (const float4*)ln_b;
  s = 0.f; s2 = 0.f;
#pragma unroll
  for (int j = 0; j < 16; ++j) {
    float4 ww = wr[tid + j * 256];
    float4 bb = br[tid + j * 256];
    float4 h;
    h.x = (x[j].x - mu) * inv * ww.x + bb.x;
    h.y = (x[j].y - mu) * inv * ww.y + bb.y;
    h.z = (x[j].z - mu) * inv * ww.z + bb.z;
    h.w = (x[j].w - mu) * inv * ww.w + bb.w;
    x[j] = h;
    s += h.x + h.y + h.z + h.w;
    s2 += h.x * h.x + h.y * h.y + h.z * h.z + h.w * h.w;
  }
  float T1 = blockSumF(s, redf);
  float T2 = blockSumF(s2, redf);
  float mu2 = T1 * (1.0f / D_SAE);
  float inv2 = rsqrtf(T2 * (1.0f / D_SAE) - mu2 * mu2 + LN_EPS);
#pragma unroll
  for (int j = 0; j < 16; ++j) {
    x[j].x = (x[j].x - mu2) * inv2;
    x[j].y = (x[j].y - mu2) * inv2;
    x[j].z = (x[j].z - mu2) * inv2;
    x[j].w = (x[j].w - mu2) * inv2;
  }

  unsigned ans = 0u;
  for (int bit = 31; bit >= 0; --bit) {
    unsigned u = ans | (1u << bit);
    unsigned bb = (u & 0x80000000u) ? (u ^ 0x80000000u) : ~u;
    float tc = __uint_as_float(bb);
    int c = 0;
#pragma unroll
    for (int j = 0; j < 16; ++j) {
      c += (x[j].x >= tc) ? 1 : 0;
      c += (x[j].y >= tc) ? 1 : 0;
      c += (x[j].z >= tc) ? 1 : 0;
      c += (x[j].w >= tc) ? 1 : 0;
    }
    c = blockSumI(c, redi);
    if (c >= TOPK) ans = u;
  }
  unsigned tb = (ans & 0x80000000u) ? (ans ^ 0x80000000u) : ~ans;
  float thr = __uint_as_float(tb);

  const float4* mr = (const float4*)fmask;
#pragma unroll
  for (int j = 0; j < NFEAT / 1024; ++j) {
    float4 m = mr[tid + j * 256];
    float4 h = x[j];
    float4 e;
    e.x = h.x * m.x / (1.0f + __expf((thr - h.x) * TEMP_INV));
    e.y = h.y * m.y / (1.0f + __expf((thr - h.y) * TEMP_INV));
    e.z = h.z * m.z / (1.0f + __expf((thr - h.z) * TEMP_INV));
    e.w = h.w * m.w / (1.0f + __expf((thr - h.w) * TEMP_INV));
    bf16x4 o;
    o[0] = (bf16_t)e.x; o[1] = (bf16_t)e.y; o[2] = (bf16_t)e.z; o[3] = (bf16_t)e.w;
    *(bf16x4*)(enc_base + (size_t)row * NFEAT + (size_t)(tid + j * 256) * 4) = o;
  }
}

// ---------------- launch ----------------
extern "C" void kernel_launch(void* const* d_in, const int* in_sizes, int n_in,
                              void* d_out, int out_size, void* d_ws, size_t ws_size,
                              hipStream_t stream) {
  const float* acts  = (const float*)d_in[0];
  const float* W_enc = (const float*)d_in[1];
  const float* W_dec = (const float*)d_in[2];
  const float* b_enc = (const float*)d_in[3];
  const float* b_dec = (const float*)d_in[4];
  const float* ln_w  = (const float*)d_in[5];
  const float* ln_b  = (const float*)d_in[6];
  const float* fmask = (const float*)d_in[7];
  float* out = (float*)d_out;
  char* ws = (char*)d_ws;

  const size_t MB = 1u << 20;
  const size_t SMALL = MB;
  const size_t SZ_WencT = (size_t)D_SAE * D_IN * 2;     // 64 MB
  const size_t SZ_WdecT = (size_t)D_IN * NFEAT * 2;     // 16 MB
  const size_t SZ_actsb = (size_t)NROWS * D_IN * 2;     // 16 MB
  const size_t SZ_enc   = (size_t)NROWS * NFEAT * 2;    // 32 MB
  const size_t ROWB_pre = (size_t)D_SAE * 4;            // 64 KB / row
  const size_t ROWB_enc = (size_t)NFEAT * 2;            // 8 KB / row

  float* scale_enc = (float*)(ws + 0);
  float* scale_dec = (float*)(ws + 64 * 1024);
  float* colpart   = (float*)(ws + 128 * 1024);

  int plan;
  size_t CH;
  const size_t baseA = SMALL + SZ_WencT + SZ_WdecT + SZ_actsb + SZ_enc;
  const size_t baseC = SMALL + SZ_WdecT + SZ_actsb + SZ_enc;
  const size_t baseD = SMALL;
  if (ws_size >= baseA + 128 * ROWB_pre) {
    plan = 0;
    CH = (ws_size - baseA) / ROWB_pre;
  } else if (ws_size >= baseC + 128 * ROWB_pre) {
    plan = 1;
    CH = (ws_size - baseC) / ROWB_pre;
  } else if (ws_size >= baseD + 128 * (ROWB_pre + ROWB_enc)) {
    plan = 2;
    CH = (ws_size - baseD) / (ROWB_pre + ROWB_enc);
  } else {
    return;
  }
  CH = (CH / 128) * 128;
  if (CH > NROWS) CH = NROWS;

  size_t off = SMALL;
  bf16_t* WencT = nullptr; bf16_t* WdecT = nullptr; bf16_t* actsb = nullptr;
  bf16_t* enc = nullptr; bf16_t* encC = nullptr; float* pre = nullptr;
  if (plan == 0) { WencT = (bf16_t*)(ws + off); off += SZ_WencT; }
  if (plan <= 1) {
    WdecT = (bf16_t*)(ws + off); off += SZ_WdecT;
    actsb = (bf16_t*)(ws + off); off += SZ_actsb;
    enc   = (bf16_t*)(ws + off); off += SZ_enc;
  }
  pre = (float*)(ws + off); off += CH * ROWB_pre;
  if (plan == 2) { encC = (bf16_t*)(ws + off); off += CH * ROWB_enc; }

  col_norm_partial<<<dim3(64, 8), 256, 0, stream>>>(W_enc, colpart);
  col_norm_finalize<<<64, 256, 0, stream>>>(colpart, scale_enc);
  row_norm_kernel<<<NFEAT / 4, 256, 0, stream>>>(W_dec, scale_dec);

  if (plan == 0)
    transpose_scale_cast<0><<<dim3(D_SAE / 64, D_IN / 64), 256, 0, stream>>>(
        W_enc, scale_enc, WencT, D_SAE, D_IN);
  if (plan <= 1) {
    transpose_scale_cast<1><<<dim3(D_IN / 64, NFEAT / 64), 256, 0, stream>>>(
        W_dec, scale_dec, WdecT, D_IN, NFEAT);
    cast_bf16_kernel<<<(NROWS * D_IN / 4 + 255) / 256, 256, 0, stream>>>(
        acts, actsb, NROWS * D_IN / 4);
  }

  for (size_t r0 = 0; r0 < NROWS; r0 += CH) {
    size_t Mi = NROWS - r0 < CH ? NROWS - r0 : CH;
    if (plan == 0) {
      if (Mi % 256 == 0)
        gemm256<<<dim3(D_SAE / 256, Mi / 256), 512, 0, stream>>>(
            actsb + r0 * D_IN, WencT, b_enc, pre, D_SAE, D_IN, D_IN, D_IN);
      else
        gemm_tile<0, 0><<<dim3(D_SAE / 128, Mi / 128), 256, 0, stream>>>(
            actsb + r0 * D_IN, WencT, nullptr, b_enc, pre, D_SAE, D_IN, D_IN, D_IN);
    } else if (plan == 1) {
      gemm_tile<0, 1><<<dim3(D_SAE / 128, Mi / 128), 256, 0, stream>>>(
          actsb + r0 * D_IN, W_enc, scale_enc, b_enc, pre, D_SAE, D_IN, D_IN, D_SAE);
    } else {
      gemm_tile<1, 1><<<dim3(D_SAE / 128, Mi / 128), 256, 0, stream>>>(
          acts + r0 * D_IN, W_enc, scale_enc, b_enc, pre, D_SAE, D_IN, D_IN, D_SAE);
    }

    bf16_t* encdst = (plan == 2) ? encC : enc + r0 * NFEAT;
    row_process<<<Mi, 256, 0, stream>>>(pre, ln_w, ln_b, fmask, encdst);

    if (plan == 2)
      gemm_tile<0, 2><<<dim3(D_IN / 128, Mi / 128), 256, 0, stream>>>(
          encC, W_dec, scale_dec, b_dec, out + r0 * D_IN, D_IN, NFEAT, NFEAT, D_IN);
  }
  if (plan != 2)
    gemm_tile<0, 0><<<dim3(D_IN / 128, NROWS / 128), 256, 0, stream>>>(
        enc, WdecT, nullptr, b_dec, out, D_IN, NFEAT, NFEAT, NFEAT);
}

// Round 4
// 677.479 us; speedup vs baseline: 1.0446x; 1.0446x over previous
//
#include <hip/hip_runtime.h>
#include <hip/hip_bf16.h>

typedef __bf16 bf16_t;
typedef __attribute__((ext_vector_type(8))) __bf16 bf16x8;
typedef __attribute__((ext_vector_type(4))) __bf16 bf16x4;
typedef __attribute__((ext_vector_type(4))) float f32x4;

#define D_IN   2048
#define D_SAE  16384
#define NROWS  4096
#define NFEAT  4096     // INIT_FEATURES (first NFEAT features unmasked; rest exactly zero)
#define TOPK   1638
#define W_EPS  1e-8f
#define LN_EPS 1e-5f
#define TEMP_INV 10.0f

// ---------------- reductions ----------------
__device__ inline float blockSumF(float v, float* red) {
#pragma unroll
  for (int o = 32; o; o >>= 1) v += __shfl_xor(v, o, 64);
  __syncthreads();
  if ((threadIdx.x & 63) == 0) red[threadIdx.x >> 6] = v;
  __syncthreads();
  return red[0] + red[1] + red[2] + red[3];
}

__device__ inline int blockSumI(int v, int* red) {
#pragma unroll
  for (int o = 32; o; o >>= 1) v += __shfl_xor(v, o, 64);
  __syncthreads();
  if ((threadIdx.x & 63) == 0) red[threadIdx.x >> 6] = v;
  __syncthreads();
  return red[0] + red[1] + red[2] + red[3];
}

// ---------------- W_enc column norms ----------------
__global__ __launch_bounds__(256) void col_norm_partial(const float* __restrict__ W,
                                                        float* __restrict__ part) {
  int col = blockIdx.x * 256 + threadIdx.x;
  int rc = blockIdx.y;
  const float* p = W + (size_t)rc * 256 * D_SAE + col;
  float s = 0.f;
#pragma unroll 8
  for (int r = 0; r < 256; ++r) {
    float v = p[(size_t)r * D_SAE];
    s += v * v;
  }
  part[(size_t)rc * D_SAE + col] = s;
}

__global__ __launch_bounds__(256) void col_norm_finalize(const float* __restrict__ part,
                                                         float* __restrict__ scale) {
  int col = blockIdx.x * 256 + threadIdx.x;
  float s = 0.f;
#pragma unroll
  for (int c = 0; c < 8; ++c) s += part[(size_t)c * D_SAE + col];
  scale[col] = 1.0f / (sqrtf(s) + W_EPS);
}

// ---------------- W_dec row norms ----------------
__global__ __launch_bounds__(256) void row_norm_kernel(const float* __restrict__ W,
                                                       float* __restrict__ scale) {
  int gw = (blockIdx.x * 256 + threadIdx.x) >> 6;
  int lane = threadIdx.x & 63;
  const float4* r4 = (const float4*)(W + (size_t)gw * D_IN);
  float s = 0.f;
#pragma unroll
  for (int i = 0; i < (D_IN / 4) / 64; ++i) {
    float4 v = r4[lane + i * 64];
    s += v.x * v.x + v.y * v.y + v.z * v.z + v.w * v.w;
  }
#pragma unroll
  for (int o = 32; o; o >>= 1) s += __shfl_xor(s, o, 64);
  if (lane == 0) scale[gw] = 1.0f / (sqrtf(s) + W_EPS);
}

// ---------------- transpose + scale + cast to bf16 ----------------
template <int SCALE_AXIS>
__global__ __launch_bounds__(256) void transpose_scale_cast(
    const float* __restrict__ in, const float* __restrict__ scale,
    bf16_t* __restrict__ out, int C, int Rout) {
  __shared__ float t[64][65];
  int c0 = blockIdx.x * 64;
  int r0 = blockIdx.y * 64;
  int tx = threadIdx.x & 63;
  int ty = threadIdx.x >> 6;
#pragma unroll
  for (int i = 0; i < 16; ++i) {
    int r = ty * 16 + i;
    float v = in[(size_t)(r0 + r) * C + (c0 + tx)];
    float sc = (SCALE_AXIS == 0) ? scale[c0 + tx] : scale[r0 + r];
    t[r][tx] = v * sc;
  }
  __syncthreads();
#pragma unroll
  for (int i = 0; i < 16; ++i) {
    int r = ty * 16 + i;
    out[(size_t)(c0 + r) * Rout + (r0 + tx)] = (bf16_t)t[tx][r];
  }
}

// ---------------- cast acts f32 -> bf16 ----------------
__global__ __launch_bounds__(256) void cast_bf16_kernel(const float* __restrict__ in,
                                                        bf16_t* __restrict__ out, int n4) {
  int i = blockIdx.x * 256 + threadIdx.x;
  if (i < n4) {
    float4 v = ((const float4*)in)[i];
    bf16x4 o;
    o[0] = (bf16_t)v.x; o[1] = (bf16_t)v.y; o[2] = (bf16_t)v.z; o[3] = (bf16_t)v.w;
    *(bf16x4*)(out + (size_t)i * 4) = o;
  }
}

__device__ inline void gload_lds16(const bf16_t* g, bf16_t* l) {
  __builtin_amdgcn_global_load_lds((__attribute__((address_space(1))) void*)g,
                                   (__attribute__((address_space(3))) void*)l,
                                   16, 0, 0);
}

// ============ 256x256 8-phase pipelined bf16 MFMA GEMM (m201 template) ============
// C[M][N] = A[M][K] * BT[N][K]^T + bias[N].  M%256==0, N%256==0, K%128==0, K>=256.
// LDS: per operand 2 dbuf x 2 halves x (128 rows x 64 k) bf16; XOR-swizzled via
// pre-swizzled global source + swizzled ds_read (both-sides, rule 21).
__global__ __launch_bounds__(512, 2) void gemm256p(
    const bf16_t* __restrict__ A, const bf16_t* __restrict__ BT,
    const float* __restrict__ bias, float* __restrict__ C,
    int N, int K, int lda, int ldb) {
  __shared__ __align__(16) bf16_t As[2][2][128 * 64];
  __shared__ __align__(16) bf16_t Bs[2][2][128 * 64];

  const int tid = threadIdx.x;
  const int lane = tid & 63;
  const int w = tid >> 6;       // 0..7
  const int wm = w >> 2;        // 0..1
  const int wn = w & 3;         // 0..3

  // XCD swizzle (bijective when nwg%8==0): contiguous chunk per XCD
  const int gx = gridDim.x, gy = gridDim.y;
  const int nwg = gx * gy;
  int orig = blockIdx.y * gx + blockIdx.x;
  int wgid = orig;
  if ((nwg & 7) == 0) wgid = (orig & 7) * (nwg >> 3) + (orig >> 3);
  const int bx = wgid / gy;
  const int by = wgid % gy;
  const long brow = (long)by * 256;
  const long bcol = (long)bx * 256;

  // staging: per half-tile (128 rows x 64 k) each thread does 2 x 16B loads.
  // wave w stages rows w*16+i*8+(lane>>3); source granule pre-swizzled.
  const int srow = lane >> 3;                      // 0..7
  const int sg = ((lane & 7) ^ srow) * 8;          // swizzled granule (elems)
  const bf16_t* a0 = A + (size_t)(brow + w * 16 + srow) * lda + sg;
  const bf16_t* b0 = BT + (size_t)(bcol + w * 16 + srow) * ldb + sg;
  const int ldsb = w * 1024;                       // elem offset of wave's region

#define STAGE_A(p_, h_, kt_)                                                   \
  do {                                                                         \
    gload_lds16(a0 + (size_t)((h_)*128 + 0) * lda + (kt_), &As[p_][h_][ldsb]); \
    gload_lds16(a0 + (size_t)((h_)*128 + 8) * lda + (kt_), &As[p_][h_][ldsb + 512]); \
  } while (0)
#define STAGE_B(p_, h_, kt_)                                                   \
  do {                                                                         \
    gload_lds16(b0 + (size_t)((h_)*128 + 0) * ldb + (kt_), &Bs[p_][h_][ldsb]); \
    gload_lds16(b0 + (size_t)((h_)*128 + 8) * ldb + (kt_), &Bs[p_][h_][ldsb + 512]); \
  } while (0)

  // fragment read offsets (byte, within a half region)
  const int fr = lane & 15;
  const int kq = (lane >> 4) * 16;
  const int xr = (fr & 7) << 4;
  const int aoffs0 = fr * 128 + (kq ^ xr);
  const int aoffs1 = fr * 128 + ((64 + kq) ^ xr);
  const int boffs0 = ((wn & 1) * 64 + fr) * 128 + (kq ^ xr);
  const int boffs1 = ((wn & 1) * 64 + fr) * 128 + ((64 + kq) ^ xr);

  bf16x8 aF[4][2], bF[4][2];
  f32x4 acc[8][4] = {};

#define RD_A(P_, MH_)                                                          \
  do {                                                                         \
    const char* aB_ = (const char*)&As[P_][wm][0] + (MH_)*8192;                \
    _Pragma("unroll") for (int m_ = 0; m_ < 4; ++m_) {                         \
      aF[m_][0] = *(const bf16x8*)(aB_ + m_ * 2048 + aoffs0);                  \
      aF[m_][1] = *(const bf16x8*)(aB_ + m_ * 2048 + aoffs1);                  \
    }                                                                          \
  } while (0)
#define RD_B(P_, N0_)                                                          \
  do {                                                                         \
    const char* bB_ = (const char*)&Bs[P_][wn >> 1][0];                        \
    _Pragma("unroll") for (int n_ = 0; n_ < 2; ++n_) {                         \
      bF[(N0_) + n_][0] = *(const bf16x8*)(bB_ + ((N0_) + n_) * 2048 + boffs0);\
      bF[(N0_) + n_][1] = *(const bf16x8*)(bB_ + ((N0_) + n_) * 2048 + boffs1);\
    }                                                                          \
  } while (0)
#define MFMA16(MH_, NP_)                                                       \
  do {                                                                         \
    _Pragma("unroll") for (int m_ = 0; m_ < 4; ++m_) {                         \
      _Pragma("unroll") for (int n_ = 0; n_ < 2; ++n_) {                       \
        acc[(MH_)*4 + m_][(NP_)*2 + n_] = __builtin_amdgcn_mfma_f32_16x16x32_bf16( \
            aF[m_][0], bF[(NP_)*2 + n_][0], acc[(MH_)*4 + m_][(NP_)*2 + n_], 0, 0, 0); \
        acc[(MH_)*4 + m_][(NP_)*2 + n_] = __builtin_amdgcn_mfma_f32_16x16x32_bf16( \
            aF[m_][1], bF[(NP_)*2 + n_][1], acc[(MH_)*4 + m_][(NP_)*2 + n_], 0, 0, 0); \
      }                                                                        \
    }                                                                          \
  } while (0)

#define VM6 asm volatile("s_waitcnt vmcnt(6)" ::: "memory")
#define VM0 asm volatile("s_waitcnt vmcnt(0)" ::: "memory")
#define LGKM8 asm volatile("s_waitcnt lgkmcnt(8)" ::: "memory")
#define NOPX (void)0

// Phase: {ds_read frags ; stage 1 half-tile ; hint} BAR lgkm0 [16 MFMA] tailvm BAR
#define PHASE(RDS, STG, HINT, TAIL, MH_, NP_)                                  \
  do {                                                                         \
    RDS;                                                                       \
    STG;                                                                       \
    HINT;                                                                      \
    __builtin_amdgcn_sched_barrier(0);                                         \
    __builtin_amdgcn_s_barrier();                                              \
    asm volatile("s_waitcnt lgkmcnt(0)" ::: "memory");                         \
    __builtin_amdgcn_sched_barrier(0);                                         \
    __builtin_amdgcn_s_setprio(1);                                             \
    MFMA16(MH_, NP_);                                                          \
    __builtin_amdgcn_s_setprio(0);                                             \
    __builtin_amdgcn_sched_barrier(0);                                         \
    TAIL;                                                                      \
    __builtin_amdgcn_s_barrier();                                              \
    __builtin_amdgcn_sched_barrier(0);                                         \
  } while (0)

  const int NITER = K >> 7;   // 2 K-tiles (of 64) per iteration

  // prologue: tile0 full (buf0), tile1 B0,B1,A0 (buf1)  [14 loads]
  STAGE_B(0, 0, 0); STAGE_B(0, 1, 0); STAGE_A(0, 0, 0); STAGE_A(0, 1, 0);
  STAGE_B(1, 0, 64); STAGE_B(1, 1, 64); STAGE_A(1, 0, 64);
  VM6;                                  // oldest 8 = all of tile0 landed
  __builtin_amdgcn_s_barrier();         // cross-wave: tile0 visible to all
  __builtin_amdgcn_sched_barrier(0);

  for (int it = 0; it < NITER - 1; ++it) {
    const int kt = it * 128;
    // tiles t=2it (buf0), t+1 (buf1); stage t+2 (buf0), t+3 (buf1)
    PHASE(RD_A(0, 0); RD_B(0, 0), STAGE_A(1, 1, kt + 64),  LGKM8, NOPX, 0, 0);
    PHASE(RD_B(0, 2),             STAGE_B(0, 0, kt + 128), NOPX,  NOPX, 0, 1);
    PHASE(RD_A(0, 1),             STAGE_B(0, 1, kt + 128), NOPX,  NOPX, 1, 0);
    PHASE(NOPX,                   STAGE_A(0, 0, kt + 128), NOPX,  VM6,  1, 1);
    PHASE(RD_A(1, 0); RD_B(1, 0), STAGE_A(0, 1, kt + 128), LGKM8, NOPX, 0, 0);
    PHASE(RD_B(1, 2),             STAGE_B(1, 0, kt + 192), NOPX,  NOPX, 0, 1);
    PHASE(RD_A(1, 1),             STAGE_B(1, 1, kt + 192), NOPX,  NOPX, 1, 0);
    PHASE(NOPX,                   STAGE_A(1, 0, kt + 192), NOPX,  VM6,  1, 1);
  }
  {
    const int kt = (NITER - 1) * 128;   // last pair: tiles NT-2, NT-1
    PHASE(RD_A(0, 0); RD_B(0, 0), STAGE_A(1, 1, kt + 64), LGKM8, NOPX, 0, 0);
    PHASE(RD_B(0, 2),             NOPX, NOPX, NOPX, 0, 1);
    PHASE(RD_A(0, 1),             NOPX, NOPX, NOPX, 1, 0);
    PHASE(NOPX,                   NOPX, NOPX, VM0,  1, 1);   // drain: all t+1 landed
    PHASE(RD_A(1, 0); RD_B(1, 0), NOPX, NOPX, NOPX, 0, 0);
    PHASE(RD_B(1, 2),             NOPX, NOPX, NOPX, 0, 1);
    PHASE(RD_A(1, 1),             NOPX, NOPX, NOPX, 1, 0);
    PHASE(NOPX,                   NOPX, NOPX, NOPX, 1, 1);
  }
#undef PHASE
#undef STAGE_A
#undef STAGE_B

  // ---- epilogue ----
  float bval[4];
#pragma unroll
  for (int n = 0; n < 4; ++n) bval[n] = bias[bcol + wn * 64 + n * 16 + fr];
#pragma unroll
  for (int m = 0; m < 8; ++m) {
#pragma unroll
    for (int r = 0; r < 4; ++r) {
      size_t row = brow + wm * 128 + m * 16 + (lane >> 4) * 4 + r;
      float* cp = C + row * (size_t)N + bcol + wn * 64 + fr;
#pragma unroll
      for (int n = 0; n < 4; ++n) cp[n * 16] = acc[m][n][r] + bval[n];
    }
  }
}

// ---------------- unified 128x128 MFMA GEMM (fallback / GEMM2) ----------------
template <int AMODE, int BMODE>
__global__ __launch_bounds__(256, 2) void gemm_tile(
    const void* __restrict__ Ap, const void* __restrict__ Bp,
    const float* __restrict__ bscale, const float* __restrict__ bias,
    float* __restrict__ C, int N, int K, int lda, int ldb) {
  __shared__ __align__(16) bf16_t As[128 * 32];
  __shared__ __align__(16) bf16_t Bs[128 * 32];
  const int tid = threadIdx.x;
  const int lane = tid & 63;
  const int wid = tid >> 6;
  const int wm = wid >> 1, wn = wid & 1;
  const long brow = (long)blockIdx.y * 128;
  const long bcol = (long)blockIdx.x * 128;

  f32x4 acc[4][4] = {};

  const bf16_t* ag = nullptr; bf16_t* al = nullptr;
  const float* af32 = nullptr;
  if (AMODE == 0) {
    ag = (const bf16_t*)Ap + (size_t)(brow + wid * 32 + (lane >> 2)) * lda + (lane & 3) * 8;
    al = &As[(wid * 32) * 32];
  } else {
    af32 = (const float*)Ap;
  }
  const bf16_t* bg = nullptr; bf16_t* bl = nullptr;
  const float* bf32 = nullptr;
  if (BMODE == 0) {
    bg = (const bf16_t*)Bp + (size_t)(bcol + wid * 32 + (lane >> 2)) * ldb + (lane & 3) * 8;
    bl = &Bs[(wid * 32) * 32];
  } else {
    bf32 = (const float*)Bp;
  }

  const int fr = lane & 15;
  const int kc = (lane >> 4) * 8;
  const int aoff0 = (wm * 64 + fr) * 32 + kc;
  const int boff0 = (wn * 64 + fr) * 32 + kc;

  for (int kt = 0; kt < K; kt += 32) {
    if (AMODE == 0) {
      gload_lds16(ag + kt, al);
      gload_lds16(ag + kt + (size_t)16 * lda, al + 16 * 32);
    } else {
#pragma unroll
      for (int i = 0; i < 4; ++i) {
        int flat = tid + i * 256;
        int r = flat >> 3;
        int k4 = flat & 7;
        float4 v = *(const float4*)&af32[(size_t)(brow + r) * lda + kt + k4 * 4];
        bf16x4 o;
        o[0] = (bf16_t)v.x; o[1] = (bf16_t)v.y; o[2] = (bf16_t)v.z; o[3] = (bf16_t)v.w;
        *(bf16x4*)&As[r * 32 + k4 * 4] = o;
      }
    }
    if (BMODE == 0) {
      gload_lds16(bg + kt, bl);
      gload_lds16(bg + kt + (size_t)16 * ldb, bl + 16 * 32);
    } else {
#pragma unroll
      for (int i = 0; i < 4; ++i) {
        int flat = tid + i * 256;
        int k = flat >> 5;
        int c4 = flat & 31;
        float4 v = *(const float4*)&bf32[(size_t)(kt + k) * ldb + bcol + c4 * 4];
        float4 sc;
        if (BMODE == 1) {
          sc = *(const float4*)&bscale[bcol + c4 * 4];
        } else {
          float s = bscale[kt + k];
          sc.x = s; sc.y = s; sc.z = s; sc.w = s;
        }
        Bs[(c4 * 4 + 0) * 32 + k] = (bf16_t)(v.x * sc.x);
        Bs[(c4 * 4 + 1) * 32 + k] = (bf16_t)(v.y * sc.y);
        Bs[(c4 * 4 + 2) * 32 + k] = (bf16_t)(v.z * sc.z);
        Bs[(c4 * 4 + 3) * 32 + k] = (bf16_t)(v.w * sc.w);
      }
    }
    __syncthreads();
    bf16x8 afr[4], bfr[4];
#pragma unroll
    for (int m = 0; m < 4; ++m) afr[m] = *(const bf16x8*)&As[aoff0 + m * 16 * 32];
#pragma unroll
    for (int n = 0; n < 4; ++n) bfr[n] = *(const bf16x8*)&Bs[boff0 + n * 16 * 32];
#pragma unroll
    for (int m = 0; m < 4; ++m)
#pragma unroll
      for (int n = 0; n < 4; ++n)
        acc[m][n] = __builtin_amdgcn_mfma_f32_16x16x32_bf16(afr[m], bfr[n], acc[m][n], 0, 0, 0);
    __syncthreads();
  }

  float bval[4];
#pragma unroll
  for (int n = 0; n < 4; ++n) bval[n] = bias[bcol + wn * 64 + n * 16 + fr];
#pragma unroll
  for (int m = 0; m < 4; ++m) {
#pragma unroll
    for (int r = 0; r < 4; ++r) {
      size_t row = brow + wm * 64 + m * 16 + (lane >> 4) * 4 + r;
      float* cp = C + row * (size_t)N + bcol + wn * 64 + fr;
#pragma unroll
      for (int n = 0; n < 4; ++n) cp[n * 16] = acc[m][n][r] + bval[n];
    }
  }
}

// ---------------- per-row: LN -> affine -> LN -> exact topK thr -> encoded ----------------
__global__ __launch_bounds__(256) void row_process(
    const float* __restrict__ pre, const float* __restrict__ ln_w,
    const float* __restrict__ ln_b, const float* __restrict__ fmask,
    bf16_t* __restrict__ enc_base) {
  __shared__ float redf[4];
  __shared__ int redi[4];
  const int tid = threadIdx.x;
  const size_t row = blockIdx.x;
  const float4* xr = (const float4*)(pre + row * D_SAE);

  float4 x[16];
  float s = 0.f, s2 = 0.f;
#pragma unroll
  for (int j = 0; j < 16; ++j) {
    float4 v = xr[tid + j * 256];
    x[j] = v;
    s += v.x + v.y + v.z + v.w;
    s2 += v.x * v.x + v.y * v.y + v.z * v.z + v.w * v.w;
  }
  float S1 = blockSumF(s, redf);
  float S2 = blockSumF(s2, redf);
  float mu = S1 * (1.0f / D_SAE);
  float var = S2 * (1.0f / D_SAE) - mu * mu;
  float inv = rsqrtf(var + LN_EPS);

  const float4* wr = (const float4*)ln_w;
  const float4* br = (const float4*)ln_b;
  s = 0.f; s2 = 0.f;
#pragma unroll
  for (int j = 0; j < 16; ++j) {
    float4 ww = wr[tid + j * 256];
    float4 bb = br[tid + j * 256];
    float4 h;
    h.x = (x[j].x - mu) * inv * ww.x + bb.x;
    h.y = (x[j].y - mu) * inv * ww.y + bb.y;
    h.z = (x[j].z - mu) * inv * ww.z + bb.z;
    h.w = (x[j].w - mu) * inv * ww.w + bb.w;
    x[j] = h;
    s += h.x + h.y + h.z + h.w;
    s2 += h.x * h.x + h.y * h.y + h.z * h.z + h.w * h.w;
  }
  float T1 = blockSumF(s, redf);
  float T2 = blockSumF(s2, redf);
  float mu2 = T1 * (1.0f / D_SAE);
  float inv2 = rsqrtf(T2 * (1.0f / D_SAE) - mu2 * mu2 + LN_EPS);
#pragma unroll
  for (int j = 0; j < 16; ++j) {
    x[j].x = (x[j].x - mu2) * inv2;
    x[j].y = (x[j].y - mu2) * inv2;
    x[j].z = (x[j].z - mu2) * inv2;
    x[j].w = (x[j].w - mu2) * inv2;
  }

  unsigned ans = 0u;
  for (int bit = 31; bit >= 0; --bit) {
    unsigned u = ans | (1u << bit);
    unsigned bb = (u & 0x80000000u) ? (u ^ 0x80000000u) : ~u;
    float tc = __uint_as_float(bb);
    int c = 0;
#pragma unroll
    for (int j = 0; j < 16; ++j) {
      c += (x[j].x >= tc) ? 1 : 0;
      c += (x[j].y >= tc) ? 1 : 0;
      c += (x[j].z >= tc) ? 1 : 0;
      c += (x[j].w >= tc) ? 1 : 0;
    }
    c = blockSumI(c, redi);
    if (c >= TOPK) ans = u;
  }
  unsigned tb = (ans & 0x80000000u) ? (ans ^ 0x80000000u) : ~ans;
  float thr = __uint_as_float(tb);

  const float4* mr = (const float4*)fmask;
#pragma unroll
  for (int j = 0; j < NFEAT / 1024; ++j) {
    float4 m = mr[tid + j * 256];
    float4 h = x[j];
    float4 e;
    e.x = h.x * m.x / (1.0f + __expf((thr - h.x) * TEMP_INV));
    e.y = h.y * m.y / (1.0f + __expf((thr - h.y) * TEMP_INV));
    e.z = h.z * m.z / (1.0f + __expf((thr - h.z) * TEMP_INV));
    e.w = h.w * m.w / (1.0f + __expf((thr - h.w) * TEMP_INV));
    bf16x4 o;
    o[0] = (bf16_t)e.x; o[1] = (bf16_t)e.y; o[2] = (bf16_t)e.z; o[3] = (bf16_t)e.w;
    *(bf16x4*)(enc_base + (size_t)row * NFEAT + (size_t)(tid + j * 256) * 4) = o;
  }
}

// ---------------- launch ----------------
extern "C" void kernel_launch(void* const* d_in, const int* in_sizes, int n_in,
                              void* d_out, int out_size, void* d_ws, size_t ws_size,
                              hipStream_t stream) {
  const float* acts  = (const float*)d_in[0];
  const float* W_enc = (const float*)d_in[1];
  const float* W_dec = (const float*)d_in[2];
  const float* b_enc = (const float*)d_in[3];
  const float* b_dec = (const float*)d_in[4];
  const float* ln_w  = (const float*)d_in[5];
  const float* ln_b  = (const float*)d_in[6];
  const float* fmask = (const float*)d_in[7];
  float* out = (float*)d_out;
  char* ws = (char*)d_ws;

  const size_t MB = 1u << 20;
  const size_t SMALL = MB;
  const size_t SZ_WencT = (size_t)D_SAE * D_IN * 2;
  const size_t SZ_WdecT = (size_t)D_IN * NFEAT * 2;
  const size_t SZ_actsb = (size_t)NROWS * D_IN * 2;
  const size_t SZ_enc   = (size_t)NROWS * NFEAT * 2;
  const size_t ROWB_pre = (size_t)D_SAE * 4;
  const size_t ROWB_enc = (size_t)NFEAT * 2;

  float* scale_enc = (float*)(ws + 0);
  float* scale_dec = (float*)(ws + 64 * 1024);
  float* colpart   = (float*)(ws + 128 * 1024);

  int plan;
  size_t CH;
  const size_t baseA = SMALL + SZ_WencT + SZ_WdecT + SZ_actsb + SZ_enc;
  const size_t baseC = SMALL + SZ_WdecT + SZ_actsb + SZ_enc;
  const size_t baseD = SMALL;
  if (ws_size >= baseA + 128 * ROWB_pre) {
    plan = 0;
    CH = (ws_size - baseA) / ROWB_pre;
  } else if (ws_size >= baseC + 128 * ROWB_pre) {
    plan = 1;
    CH = (ws_size - baseC) / ROWB_pre;
  } else if (ws_size >= baseD + 128 * (ROWB_pre + ROWB_enc)) {
    plan = 2;
    CH = (ws_size - baseD) / (ROWB_pre + ROWB_enc);
  } else {
    return;
  }
  CH = (CH / 128) * 128;
  if (CH > NROWS) CH = NROWS;

  size_t off = SMALL;
  bf16_t* WencT = nullptr; bf16_t* WdecT = nullptr; bf16_t* actsb = nullptr;
  bf16_t* enc = nullptr; bf16_t* encC = nullptr; float* pre = nullptr;
  if (plan == 0) { WencT = (bf16_t*)(ws + off); off += SZ_WencT; }
  if (plan <= 1) {
    WdecT = (bf16_t*)(ws + off); off += SZ_WdecT;
    actsb = (bf16_t*)(ws + off); off += SZ_actsb;
    enc   = (bf16_t*)(ws + off); off += SZ_enc;
  }
  pre = (float*)(ws + off); off += CH * ROWB_pre;
  if (plan == 2) { encC = (bf16_t*)(ws + off); off += CH * ROWB_enc; }

  col_norm_partial<<<dim3(64, 8), 256, 0, stream>>>(W_enc, colpart);
  col_norm_finalize<<<64, 256, 0, stream>>>(colpart, scale_enc);
  row_norm_kernel<<<NFEAT / 4, 256, 0, stream>>>(W_dec, scale_dec);

  if (plan == 0)
    transpose_scale_cast<0><<<dim3(D_SAE / 64, D_IN / 64), 256, 0, stream>>>(
        W_enc, scale_enc, WencT, D_SAE, D_IN);
  if (plan <= 1) {
    transpose_scale_cast<1><<<dim3(D_IN / 64, NFEAT / 64), 256, 0, stream>>>(
        W_dec, scale_dec, WdecT, D_IN, NFEAT);
    cast_bf16_kernel<<<(NROWS * D_IN / 4 + 255) / 256, 256, 0, stream>>>(
        acts, actsb, NROWS * D_IN / 4);
  }

  for (size_t r0 = 0; r0 < NROWS; r0 += CH) {
    size_t Mi = NROWS - r0 < CH ? NROWS - r0 : CH;
    if (plan == 0) {
      if (Mi % 256 == 0)
        gemm256p<<<dim3(D_SAE / 256, Mi / 256), 512, 0, stream>>>(
            actsb + r0 * D_IN, WencT, b_enc, pre, D_SAE, D_IN, D_IN, D_IN);
      else
        gemm_tile<0, 0><<<dim3(D_SAE / 128, Mi / 128), 256, 0, stream>>>(
            actsb + r0 * D_IN, WencT, nullptr, b_enc, pre, D_SAE, D_IN, D_IN, D_IN);
    } else if (plan == 1) {
      gemm_tile<0, 1><<<dim3(D_SAE / 128, Mi / 128), 256, 0, stream>>>(
          actsb + r0 * D_IN, W_enc, scale_enc, b_enc, pre, D_SAE, D_IN, D_IN, D_SAE);
    } else {
      gemm_tile<1, 1><<<dim3(D_SAE / 128, Mi / 128), 256, 0, stream>>>(
          acts + r0 * D_IN, W_enc, scale_enc, b_enc, pre, D_SAE, D_IN, D_IN, D_SAE);
    }

    bf16_t* encdst = (plan == 2) ? encC : enc + r0 * NFEAT;
    row_process<<<Mi, 256, 0, stream>>>(pre, ln_w, ln_b, fmask, encdst);

    if (plan == 2)
      gemm_tile<0, 2><<<dim3(D_IN / 128, Mi / 128), 256, 0, stream>>>(
          encC, W_dec, scale_dec, b_dec, out + r0 * D_IN, D_IN, NFEAT, NFEAT, D_IN);
  }
  if (plan != 2)
    gemm_tile<0, 0><<<dim3(D_IN / 128, NROWS / 128), 256, 0, stream>>>(
        enc, WdecT, nullptr, b_dec, out, D_IN, NFEAT, NFEAT, NFEAT);
}

// Round 5
// 640.878 us; speedup vs baseline: 1.1043x; 1.0571x over previous
//
#include <hip/hip_runtime.h>
#include <hip/hip_bf16.h>

typedef __bf16 bf16_t;
typedef __attribute__((ext_vector_type(8))) __bf16 bf16x8;
typedef __attribute__((ext_vector_type(4))) __bf16 bf16x4;
typedef __attribute__((ext_vector_type(4))) float f32x4;

#define D_IN   2048
#define D_SAE  16384
#define NROWS  4096
#define NFEAT  4096     // INIT_FEATURES (first NFEAT features unmasked; rest exactly zero)
#define TOPK   1638
#define W_EPS  1e-8f
#define LN_EPS 1e-5f
#define TEMP_INV 10.0f

// ---------------- reductions ----------------
__device__ inline float blockSumF(float v, float* red) {
#pragma unroll
  for (int o = 32; o; o >>= 1) v += __shfl_xor(v, o, 64);
  __syncthreads();
  if ((threadIdx.x & 63) == 0) red[threadIdx.x >> 6] = v;
  __syncthreads();
  return red[0] + red[1] + red[2] + red[3];
}

__device__ inline int blockSumI(int v, int* red) {
#pragma unroll
  for (int o = 32; o; o >>= 1) v += __shfl_xor(v, o, 64);
  __syncthreads();
  if ((threadIdx.x & 63) == 0) red[threadIdx.x >> 6] = v;
  __syncthreads();
  return red[0] + red[1] + red[2] + red[3];
}

// ---------------- W_enc column norms ----------------
__global__ __launch_bounds__(256) void col_norm_partial(const float* __restrict__ W,
                                                        float* __restrict__ part) {
  int col = blockIdx.x * 256 + threadIdx.x;
  int rc = blockIdx.y;
  const float* p = W + (size_t)rc * 256 * D_SAE + col;
  float s = 0.f;
#pragma unroll 8
  for (int r = 0; r < 256; ++r) {
    float v = p[(size_t)r * D_SAE];
    s += v * v;
  }
  part[(size_t)rc * D_SAE + col] = s;
}

__global__ __launch_bounds__(256) void col_norm_finalize(const float* __restrict__ part,
                                                         float* __restrict__ scale) {
  int col = blockIdx.x * 256 + threadIdx.x;
  float s = 0.f;
#pragma unroll
  for (int c = 0; c < 8; ++c) s += part[(size_t)c * D_SAE + col];
  scale[col] = 1.0f / (sqrtf(s) + W_EPS);
}

// ---------------- W_dec row norms ----------------
__global__ __launch_bounds__(256) void row_norm_kernel(const float* __restrict__ W,
                                                       float* __restrict__ scale) {
  int gw = (blockIdx.x * 256 + threadIdx.x) >> 6;
  int lane = threadIdx.x & 63;
  const float4* r4 = (const float4*)(W + (size_t)gw * D_IN);
  float s = 0.f;
#pragma unroll
  for (int i = 0; i < (D_IN / 4) / 64; ++i) {
    float4 v = r4[lane + i * 64];
    s += v.x * v.x + v.y * v.y + v.z * v.z + v.w * v.w;
  }
#pragma unroll
  for (int o = 32; o; o >>= 1) s += __shfl_xor(s, o, 64);
  if (lane == 0) scale[gw] = 1.0f / (sqrtf(s) + W_EPS);
}

// ---------------- transpose (+optional scale) + cast to bf16 ----------------
// SCALE_AXIS: -1 none, 0 per input col, 1 per input row
template <int SCALE_AXIS>
__global__ __launch_bounds__(256) void transpose_scale_cast(
    const float* __restrict__ in, const float* __restrict__ scale,
    bf16_t* __restrict__ out, int C, int Rout) {
  __shared__ float t[64][65];
  int c0 = blockIdx.x * 64;
  int r0 = blockIdx.y * 64;
  int tx = threadIdx.x & 63;
  int ty = threadIdx.x >> 6;
#pragma unroll
  for (int i = 0; i < 16; ++i) {
    int r = ty * 16 + i;
    float v = in[(size_t)(r0 + r) * C + (c0 + tx)];
    float sc = (SCALE_AXIS == 0) ? scale[c0 + tx]
             : (SCALE_AXIS == 1) ? scale[r0 + r] : 1.0f;
    t[r][tx] = v * sc;
  }
  __syncthreads();
#pragma unroll
  for (int i = 0; i < 16; ++i) {
    int r = ty * 16 + i;
    out[(size_t)(c0 + r) * Rout + (r0 + tx)] = (bf16_t)t[tx][r];
  }
}

// ---------------- cast acts f32 -> bf16 ----------------
__global__ __launch_bounds__(256) void cast_bf16_kernel(const float* __restrict__ in,
                                                        bf16_t* __restrict__ out, int n4) {
  int i = blockIdx.x * 256 + threadIdx.x;
  if (i < n4) {
    float4 v = ((const float4*)in)[i];
    bf16x4 o;
    o[0] = (bf16_t)v.x; o[1] = (bf16_t)v.y; o[2] = (bf16_t)v.z; o[3] = (bf16_t)v.w;
    *(bf16x4*)(out + (size_t)i * 4) = o;
  }
}

// ---------------- combine: out = p0 + p1 + bias[col] ----------------
__global__ __launch_bounds__(256) void combine_kernel(const float* __restrict__ p0,
                                                      const float* __restrict__ p1,
                                                      const float* __restrict__ bias,
                                                      float* __restrict__ out, int n4) {
  int i = blockIdx.x * 256 + threadIdx.x;
  if (i < n4) {
    float4 a = ((const float4*)p0)[i];
    float4 b = ((const float4*)p1)[i];
    float4 c = ((const float4*)bias)[i & (D_IN / 4 - 1)];
    float4 o;
    o.x = a.x + b.x + c.x; o.y = a.y + b.y + c.y;
    o.z = a.z + b.z + c.z; o.w = a.w + b.w + c.w;
    ((float4*)out)[i] = o;
  }
}

__device__ inline void gload_lds16(const bf16_t* g, bf16_t* l) {
  __builtin_amdgcn_global_load_lds((__attribute__((address_space(1))) void*)g,
                                   (__attribute__((address_space(3))) void*)l,
                                   16, 0, 0);
}

// ============ 256x256 8-phase pipelined bf16 MFMA GEMM (m201 template) ============
// Cz = A[:, z*K:(z+1)*K] * BT[:, z*K:(z+1)*K]^T  for z = blockIdx.z.
// BF16_OUT: C stored as bf16 (no bias); else f32 (no bias), C offset z*czstride.
// M%256==0, N%256==0, K%128==0, K>=256.
template <bool BF16_OUT>
__global__ __launch_bounds__(512, 2) void gemm256p(
    const bf16_t* __restrict__ A, const bf16_t* __restrict__ BT,
    void* __restrict__ Cv, int N, int K, int lda, int ldb, size_t czstride) {
  __shared__ __align__(16) bf16_t As[2][2][128 * 64];
  __shared__ __align__(16) bf16_t Bs[2][2][128 * 64];

  const int tid = threadIdx.x;
  const int lane = tid & 63;
  const int w = tid >> 6;       // 0..7
  const int wm = w >> 2;        // 0..1
  const int wn = w & 3;         // 0..3

  const int z = blockIdx.z;
  A += (size_t)z * K;
  BT += (size_t)z * K;

  // XCD swizzle (bijective when nwg%8==0): contiguous chunk per XCD
  const int gx = gridDim.x, gy = gridDim.y;
  const int nwg = gx * gy;
  int orig = blockIdx.y * gx + blockIdx.x;
  int wgid = orig;
  if ((nwg & 7) == 0) wgid = (orig & 7) * (nwg >> 3) + (orig >> 3);
  const int bx = wgid / gy;
  const int by = wgid % gy;
  const long brow = (long)by * 256;
  const long bcol = (long)bx * 256;

  // staging: per half-tile (128 rows x 64 k) each thread does 2 x 16B loads.
  const int srow = lane >> 3;                      // 0..7
  const int sg = ((lane & 7) ^ srow) * 8;          // swizzled granule (elems)
  const bf16_t* a0 = A + (size_t)(brow + w * 16 + srow) * lda + sg;
  const bf16_t* b0 = BT + (size_t)(bcol + w * 16 + srow) * ldb + sg;
  const int ldsb = w * 1024;                       // elem offset of wave's region

#define STAGE_A(p_, h_, kt_)                                                   \
  do {                                                                         \
    gload_lds16(a0 + (size_t)((h_)*128 + 0) * lda + (kt_), &As[p_][h_][ldsb]); \
    gload_lds16(a0 + (size_t)((h_)*128 + 8) * lda + (kt_), &As[p_][h_][ldsb + 512]); \
  } while (0)
#define STAGE_B(p_, h_, kt_)                                                   \
  do {                                                                         \
    gload_lds16(b0 + (size_t)((h_)*128 + 0) * ldb + (kt_), &Bs[p_][h_][ldsb]); \
    gload_lds16(b0 + (size_t)((h_)*128 + 8) * ldb + (kt_), &Bs[p_][h_][ldsb + 512]); \
  } while (0)

  // fragment read offsets (byte, within a half region)
  const int fr = lane & 15;
  const int kq = (lane >> 4) * 16;
  const int xr = (fr & 7) << 4;
  const int aoffs0 = fr * 128 + (kq ^ xr);
  const int aoffs1 = fr * 128 + ((64 + kq) ^ xr);
  const int boffs0 = ((wn & 1) * 64 + fr) * 128 + (kq ^ xr);
  const int boffs1 = ((wn & 1) * 64 + fr) * 128 + ((64 + kq) ^ xr);

  bf16x8 aF[4][2], bF[4][2];
  f32x4 acc[8][4] = {};

#define RD_A(P_, MH_)                                                          \
  do {                                                                         \
    const char* aB_ = (const char*)&As[P_][wm][0] + (MH_)*8192;                \
    _Pragma("unroll") for (int m_ = 0; m_ < 4; ++m_) {                         \
      aF[m_][0] = *(const bf16x8*)(aB_ + m_ * 2048 + aoffs0);                  \
      aF[m_][1] = *(const bf16x8*)(aB_ + m_ * 2048 + aoffs1);                  \
    }                                                                          \
  } while (0)
#define RD_B(P_, N0_)                                                          \
  do {                                                                         \
    const char* bB_ = (const char*)&Bs[P_][wn >> 1][0];                        \
    _Pragma("unroll") for (int n_ = 0; n_ < 2; ++n_) {                         \
      bF[(N0_) + n_][0] = *(const bf16x8*)(bB_ + ((N0_) + n_) * 2048 + boffs0);\
      bF[(N0_) + n_][1] = *(const bf16x8*)(bB_ + ((N0_) + n_) * 2048 + boffs1);\
    }                                                                          \
  } while (0)
#define MFMA16(MH_, NP_)                                                       \
  do {                                                                         \
    _Pragma("unroll") for (int m_ = 0; m_ < 4; ++m_) {                         \
      _Pragma("unroll") for (int n_ = 0; n_ < 2; ++n_) {                       \
        acc[(MH_)*4 + m_][(NP_)*2 + n_] = __builtin_amdgcn_mfma_f32_16x16x32_bf16( \
            aF[m_][0], bF[(NP_)*2 + n_][0], acc[(MH_)*4 + m_][(NP_)*2 + n_], 0, 0, 0); \
        acc[(MH_)*4 + m_][(NP_)*2 + n_] = __builtin_amdgcn_mfma_f32_16x16x32_bf16( \
            aF[m_][1], bF[(NP_)*2 + n_][1], acc[(MH_)*4 + m_][(NP_)*2 + n_], 0, 0, 0); \
      }                                                                        \
    }                                                                          \
  } while (0)

#define VM6 asm volatile("s_waitcnt vmcnt(6)" ::: "memory")
#define VM0 asm volatile("s_waitcnt vmcnt(0)" ::: "memory")
#define LGKM8 asm volatile("s_waitcnt lgkmcnt(8)" ::: "memory")
#define NOPX (void)0

// Phase: {ds_read frags ; stage 1 half-tile ; hint} BAR lgkm0 [16 MFMA] tailvm BAR
// No sched_barrier pins: memory ordering held by asm "memory" clobbers; MFMA
// ordering by register deps (compiler inserts its own lgkmcnt for the reads).
#define PHASE(RDS, STG, HINT, TAIL, MH_, NP_)                                  \
  do {                                                                         \
    RDS;                                                                       \
    STG;                                                                       \
    HINT;                                                                      \
    __builtin_amdgcn_s_barrier();                                              \
    asm volatile("s_waitcnt lgkmcnt(0)" ::: "memory");                         \
    __builtin_amdgcn_s_setprio(1);                                             \
    MFMA16(MH_, NP_);                                                          \
    __builtin_amdgcn_s_setprio(0);                                             \
    TAIL;                                                                      \
    __builtin_amdgcn_s_barrier();                                              \
  } while (0)

  const int NITER = K >> 7;   // 2 K-tiles (of 64) per iteration

  // prologue: tile0 full (buf0), tile1 B0,B1,A0 (buf1)  [14 loads]
  STAGE_B(0, 0, 0); STAGE_B(0, 1, 0); STAGE_A(0, 0, 0); STAGE_A(0, 1, 0);
  STAGE_B(1, 0, 64); STAGE_B(1, 1, 64); STAGE_A(1, 0, 64);
  VM6;                                  // oldest 8 = all of tile0 landed
  __builtin_amdgcn_s_barrier();         // cross-wave: tile0 visible to all

  for (int it = 0; it < NITER - 1; ++it) {
    const int kt = it * 128;
    // tiles t=2it (buf0), t+1 (buf1); stage t+2 (buf0), t+3 (buf1)
    PHASE(RD_A(0, 0); RD_B(0, 0), STAGE_A(1, 1, kt + 64),  LGKM8, NOPX, 0, 0);
    PHASE(RD_B(0, 2),             STAGE_B(0, 0, kt + 128), NOPX,  NOPX, 0, 1);
    PHASE(RD_A(0, 1),             STAGE_B(0, 1, kt + 128), NOPX,  NOPX, 1, 0);
    PHASE(NOPX,                   STAGE_A(0, 0, kt + 128), NOPX,  VM6,  1, 1);
    PHASE(RD_A(1, 0); RD_B(1, 0), STAGE_A(0, 1, kt + 128), LGKM8, NOPX, 0, 0);
    PHASE(RD_B(1, 2),             STAGE_B(1, 0, kt + 192), NOPX,  NOPX, 0, 1);
    PHASE(RD_A(1, 1),             STAGE_B(1, 1, kt + 192), NOPX,  NOPX, 1, 0);
    PHASE(NOPX,                   STAGE_A(1, 0, kt + 192), NOPX,  VM6,  1, 1);
  }
  {
    const int kt = (NITER - 1) * 128;   // last pair: tiles NT-2, NT-1
    PHASE(RD_A(0, 0); RD_B(0, 0), STAGE_A(1, 1, kt + 64), LGKM8, NOPX, 0, 0);
    PHASE(RD_B(0, 2),             NOPX, NOPX, NOPX, 0, 1);
    PHASE(RD_A(0, 1),             NOPX, NOPX, NOPX, 1, 0);
    PHASE(NOPX,                   NOPX, NOPX, VM0,  1, 1);   // drain: all t+1 landed
    PHASE(RD_A(1, 0); RD_B(1, 0), NOPX, NOPX, NOPX, 0, 0);
    PHASE(RD_B(1, 2),             NOPX, NOPX, NOPX, 0, 1);
    PHASE(RD_A(1, 1),             NOPX, NOPX, NOPX, 1, 0);
    PHASE(NOPX,                   NOPX, NOPX, NOPX, 1, 1);
  }
#undef PHASE
#undef STAGE_A
#undef STAGE_B

  // ---- epilogue ----
#pragma unroll
  for (int m = 0; m < 8; ++m) {
#pragma unroll
    for (int r = 0; r < 4; ++r) {
      size_t row = brow + wm * 128 + m * 16 + (lane >> 4) * 4 + r;
      if (BF16_OUT) {
        bf16_t* cp = (bf16_t*)Cv + row * (size_t)N + bcol + wn * 64 + fr;
#pragma unroll
        for (int n = 0; n < 4; ++n) cp[n * 16] = (bf16_t)acc[m][n][r];
      } else {
        float* cp = (float*)Cv + z * czstride + row * (size_t)N + bcol + wn * 64 + fr;
#pragma unroll
        for (int n = 0; n < 4; ++n) cp[n * 16] = acc[m][n][r];
      }
    }
  }
}

// ---------------- unified 128x128 MFMA GEMM (fallback plans) ----------------
template <int AMODE, int BMODE>
__global__ __launch_bounds__(256, 2) void gemm_tile(
    const void* __restrict__ Ap, const void* __restrict__ Bp,
    const float* __restrict__ bscale, const float* __restrict__ bias,
    float* __restrict__ C, int N, int K, int lda, int ldb) {
  __shared__ __align__(16) bf16_t As[128 * 32];
  __shared__ __align__(16) bf16_t Bs[128 * 32];
  const int tid = threadIdx.x;
  const int lane = tid & 63;
  const int wid = tid >> 6;
  const int wm = wid >> 1, wn = wid & 1;
  const long brow = (long)blockIdx.y * 128;
  const long bcol = (long)blockIdx.x * 128;

  f32x4 acc[4][4] = {};

  const bf16_t* ag = nullptr; bf16_t* al = nullptr;
  const float* af32 = nullptr;
  if (AMODE == 0) {
    ag = (const bf16_t*)Ap + (size_t)(brow + wid * 32 + (lane >> 2)) * lda + (lane & 3) * 8;
    al = &As[(wid * 32) * 32];
  } else {
    af32 = (const float*)Ap;
  }
  const bf16_t* bg = nullptr; bf16_t* bl = nullptr;
  const float* bf32 = nullptr;
  if (BMODE == 0) {
    bg = (const bf16_t*)Bp + (size_t)(bcol + wid * 32 + (lane >> 2)) * ldb + (lane & 3) * 8;
    bl = &Bs[(wid * 32) * 32];
  } else {
    bf32 = (const float*)Bp;
  }

  const int fr = lane & 15;
  const int kc = (lane >> 4) * 8;
  const int aoff0 = (wm * 64 + fr) * 32 + kc;
  const int boff0 = (wn * 64 + fr) * 32 + kc;

  for (int kt = 0; kt < K; kt += 32) {
    if (AMODE == 0) {
      gload_lds16(ag + kt, al);
      gload_lds16(ag + kt + (size_t)16 * lda, al + 16 * 32);
    } else {
#pragma unroll
      for (int i = 0; i < 4; ++i) {
        int flat = tid + i * 256;
        int r = flat >> 3;
        int k4 = flat & 7;
        float4 v = *(const float4*)&af32[(size_t)(brow + r) * lda + kt + k4 * 4];
        bf16x4 o;
        o[0] = (bf16_t)v.x; o[1] = (bf16_t)v.y; o[2] = (bf16_t)v.z; o[3] = (bf16_t)v.w;
        *(bf16x4*)&As[r * 32 + k4 * 4] = o;
      }
    }
    if (BMODE == 0) {
      gload_lds16(bg + kt, bl);
      gload_lds16(bg + kt + (size_t)16 * ldb, bl + 16 * 32);
    } else {
#pragma unroll
      for (int i = 0; i < 4; ++i) {
        int flat = tid + i * 256;
        int k = flat >> 5;
        int c4 = flat & 31;
        float4 v = *(const float4*)&bf32[(size_t)(kt + k) * ldb + bcol + c4 * 4];
        float4 sc;
        if (BMODE == 1) {
          sc = *(const float4*)&bscale[bcol + c4 * 4];
        } else {
          float s = bscale[kt + k];
          sc.x = s; sc.y = s; sc.z = s; sc.w = s;
        }
        Bs[(c4 * 4 + 0) * 32 + k] = (bf16_t)(v.x * sc.x);
        Bs[(c4 * 4 + 1) * 32 + k] = (bf16_t)(v.y * sc.y);
        Bs[(c4 * 4 + 2) * 32 + k] = (bf16_t)(v.z * sc.z);
        Bs[(c4 * 4 + 3) * 32 + k] = (bf16_t)(v.w * sc.w);
      }
    }
    __syncthreads();
    bf16x8 afr[4], bfr[4];
#pragma unroll
    for (int m = 0; m < 4; ++m) afr[m] = *(const bf16x8*)&As[aoff0 + m * 16 * 32];
#pragma unroll
    for (int n = 0; n < 4; ++n) bfr[n] = *(const bf16x8*)&Bs[boff0 + n * 16 * 32];
#pragma unroll
    for (int m = 0; m < 4; ++m)
#pragma unroll
      for (int n = 0; n < 4; ++n)
        acc[m][n] = __builtin_amdgcn_mfma_f32_16x16x32_bf16(afr[m], bfr[n], acc[m][n], 0, 0, 0);
    __syncthreads();
  }

  float bval[4];
#pragma unroll
  for (int n = 0; n < 4; ++n) bval[n] = bias ? bias[bcol + wn * 64 + n * 16 + fr] : 0.0f;
#pragma unroll
  for (int m = 0; m < 4; ++m) {
#pragma unroll
    for (int r = 0; r < 4; ++r) {
      size_t row = brow + wm * 64 + m * 16 + (lane >> 4) * 4 + r;
      float* cp = C + row * (size_t)N + bcol + wn * 64 + fr;
#pragma unroll
      for (int n = 0; n < 4; ++n) cp[n * 16] = acc[m][n][r] + bval[n];
    }
  }
}

// ---------------- per-row: (scale+bias) -> LN -> affine -> LN -> topK -> encoded ----------------
// MODE 0: pre is bf16 raw dot; apply x = pre*senc + b_enc here; fold sdec into enc.
// MODE 1: pre is f32 already scaled+biased; no folds (fallback plans).
template <int MODE>
__global__ __launch_bounds__(256) void row_process(
    const void* __restrict__ prev, const float* __restrict__ senc,
    const float* __restrict__ b_enc, const float* __restrict__ ln_w,
    const float* __restrict__ ln_b, const float* __restrict__ fmask,
    const float* __restrict__ sdec, bf16_t* __restrict__ enc_base) {
  __shared__ float redf[4];
  __shared__ int redi[4];
  const int tid = threadIdx.x;
  const size_t row = blockIdx.x;

  float4 x[16];
  float s = 0.f, s2 = 0.f;
  if (MODE == 0) {
    const bf16x8* xr = (const bf16x8*)((const bf16_t*)prev + row * D_SAE);
    const float4* s4 = (const float4*)senc;
    const float4* b4 = (const float4*)b_enc;
#pragma unroll
    for (int jj = 0; jj < 8; ++jj) {
      bf16x8 v = xr[tid + jj * 256];
      int i4 = (tid + jj * 256) * 2;
      float4 sa = s4[i4], sb = s4[i4 + 1];
      float4 ba = b4[i4], bb = b4[i4 + 1];
      float4 lo, hi;
      lo.x = (float)v[0] * sa.x + ba.x;
      lo.y = (float)v[1] * sa.y + ba.y;
      lo.z = (float)v[2] * sa.z + ba.z;
      lo.w = (float)v[3] * sa.w + ba.w;
      hi.x = (float)v[4] * sb.x + bb.x;
      hi.y = (float)v[5] * sb.y + bb.y;
      hi.z = (float)v[6] * sb.z + bb.z;
      hi.w = (float)v[7] * sb.w + bb.w;
      x[2 * jj] = lo; x[2 * jj + 1] = hi;
      s += lo.x + lo.y + lo.z + lo.w + hi.x + hi.y + hi.z + hi.w;
      s2 += lo.x * lo.x + lo.y * lo.y + lo.z * lo.z + lo.w * lo.w +
            hi.x * hi.x + hi.y * hi.y + hi.z * hi.z + hi.w * hi.w;
    }
  } else {
    const float4* xr = (const float4*)((const float*)prev + row * D_SAE);
#pragma unroll
    for (int j = 0; j < 16; ++j) {
      float4 v = xr[tid + j * 256];
      x[j] = v;
      s += v.x + v.y + v.z + v.w;
      s2 += v.x * v.x + v.y * v.y + v.z * v.z + v.w * v.w;
    }
  }
  float S1 = blockSumF(s, redf);
  float S2 = blockSumF(s2, redf);
  float mu = S1 * (1.0f / D_SAE);
  float var = S2 * (1.0f / D_SAE) - mu * mu;
  float inv = rsqrtf(var + LN_EPS);

#define IDX4(j) ((MODE == 0) ? ((tid + ((j) >> 1) * 256) * 2 + ((j) & 1)) : (tid + (j) * 256))
  const float4* wr = (const float4*)ln_w;
  const float4* br = (const float4*)ln_b;
  s = 0.f; s2 = 0.f;
#pragma unroll
  for (int j = 0; j < 16; ++j) {
    float4 ww = wr[IDX4(j)];
    float4 bb = br[IDX4(j)];
    float4 h;
    h.x = (x[j].x - mu) * inv * ww.x + bb.x;
    h.y = (x[j].y - mu) * inv * ww.y + bb.y;
    h.z = (x[j].z - mu) * inv * ww.z + bb.z;
    h.w = (x[j].w - mu) * inv * ww.w + bb.w;
    x[j] = h;
    s += h.x + h.y + h.z + h.w;
    s2 += h.x * h.x + h.y * h.y + h.z * h.z + h.w * h.w;
  }
  float T1 = blockSumF(s, redf);
  float T2 = blockSumF(s2, redf);
  float mu2 = T1 * (1.0f / D_SAE);
  float inv2 = rsqrtf(T2 * (1.0f / D_SAE) - mu2 * mu2 + LN_EPS);
#pragma unroll
  for (int j = 0; j < 16; ++j) {
    x[j].x = (x[j].x - mu2) * inv2;
    x[j].y = (x[j].y - mu2) * inv2;
    x[j].z = (x[j].z - mu2) * inv2;
    x[j].w = (x[j].w - mu2) * inv2;
  }

  unsigned ans = 0u;
  for (int bit = 31; bit >= 0; --bit) {
    unsigned u = ans | (1u << bit);
    unsigned bb = (u & 0x80000000u) ? (u ^ 0x80000000u) : ~u;
    float tc = __uint_as_float(bb);
    int c = 0;
#pragma unroll
    for (int j = 0; j < 16; ++j) {
      c += (x[j].x >= tc) ? 1 : 0;
      c += (x[j].y >= tc) ? 1 : 0;
      c += (x[j].z >= tc) ? 1 : 0;
      c += (x[j].w >= tc) ? 1 : 0;
    }
    c = blockSumI(c, redi);
    if (c >= TOPK) ans = u;
  }
  unsigned tb = (ans & 0x80000000u) ? (ans ^ 0x80000000u) : ~ans;
  float thr = __uint_as_float(tb);

  const float4* mr = (const float4*)fmask;
  if (MODE == 0) {
    const float4* d4 = (const float4*)sdec;
#pragma unroll
    for (int jj = 0; jj < 2; ++jj) {   // elems (tid+jj*256)*8 cover 0..4095
      int i4 = (tid + jj * 256) * 2;
      float4 m0 = mr[i4], m1 = mr[i4 + 1];
      float4 d0 = d4[i4], d1 = d4[i4 + 1];
      float4 a = x[2 * jj], b = x[2 * jj + 1];
      bf16x8 o;
      o[0] = (bf16_t)(a.x * m0.x / (1.0f + __expf((thr - a.x) * TEMP_INV)) * d0.x);
      o[1] = (bf16_t)(a.y * m0.y / (1.0f + __expf((thr - a.y) * TEMP_INV)) * d0.y);
      o[2] = (bf16_t)(a.z * m0.z / (1.0f + __expf((thr - a.z) * TEMP_INV)) * d0.z);
      o[3] = (bf16_t)(a.w * m0.w / (1.0f + __expf((thr - a.w) * TEMP_INV)) * d0.w);
      o[4] = (bf16_t)(b.x * m1.x / (1.0f + __expf((thr - b.x) * TEMP_INV)) * d1.x);
      o[5] = (bf16_t)(b.y * m1.y / (1.0f + __expf((thr - b.y) * TEMP_INV)) * d1.y);
      o[6] = (bf16_t)(b.z * m1.z / (1.0f + __expf((thr - b.z) * TEMP_INV)) * d1.z);
      o[7] = (bf16_t)(b.w * m1.w / (1.0f + __expf((thr - b.w) * TEMP_INV)) * d1.w);
      ((bf16x8*)(enc_base + row * NFEAT))[tid + jj * 256] = o;
    }
  } else {
#pragma unroll
    for (int j = 0; j < NFEAT / 1024; ++j) {
      float4 m = mr[tid + j * 256];
      float4 h = x[j];
      float4 e;
      e.x = h.x * m.x / (1.0f + __expf((thr - h.x) * TEMP_INV));
      e.y = h.y * m.y / (1.0f + __expf((thr - h.y) * TEMP_INV));
      e.z = h.z * m.z / (1.0f + __expf((thr - h.z) * TEMP_INV));
      e.w = h.w * m.w / (1.0f + __expf((thr - h.w) * TEMP_INV));
      bf16x4 o;
      o[0] = (bf16_t)e.x; o[1] = (bf16_t)e.y; o[2] = (bf16_t)e.z; o[3] = (bf16_t)e.w;
      *(bf16x4*)(enc_base + row * NFEAT + (size_t)(tid + j * 256) * 4) = o;
    }
  }
#undef IDX4
}

// ---------------- launch ----------------
extern "C" void kernel_launch(void* const* d_in, const int* in_sizes, int n_in,
                              void* d_out, int out_size, void* d_ws, size_t ws_size,
                              hipStream_t stream) {
  const float* acts  = (const float*)d_in[0];
  const float* W_enc = (const float*)d_in[1];
  const float* W_dec = (const float*)d_in[2];
  const float* b_enc = (const float*)d_in[3];
  const float* b_dec = (const float*)d_in[4];
  const float* ln_w  = (const float*)d_in[5];
  const float* ln_b  = (const float*)d_in[6];
  const float* fmask = (const float*)d_in[7];
  float* out = (float*)d_out;
  char* ws = (char*)d_ws;

  const size_t MB = 1u << 20;
  const size_t SMALL = MB;
  const size_t SZ_WencT = (size_t)D_SAE * D_IN * 2;     // 64 MB
  const size_t SZ_WdecT = (size_t)D_IN * NFEAT * 2;     // 16 MB
  const size_t SZ_actsb = (size_t)NROWS * D_IN * 2;     // 16 MB
  const size_t SZ_enc   = (size_t)NROWS * NFEAT * 2;    // 32 MB
  const size_t SZ_part  = (size_t)NROWS * D_IN * 4 * 2; // 64 MB (two K-split partials)
  const size_t ROWB_preb = (size_t)D_SAE * 2;           // 32 KB / row (bf16, plan 0)
  const size_t ROWB_pref = (size_t)D_SAE * 4;           // 64 KB / row (f32, plans 1/2)
  const size_t ROWB_enc  = (size_t)NFEAT * 2;

  float* scale_enc = (float*)(ws + 0);
  float* scale_dec = (float*)(ws + 64 * 1024);
  float* colpart   = (float*)(ws + 128 * 1024);

  int plan;
  size_t CH;
  const size_t baseA = SMALL + SZ_WencT + SZ_WdecT + SZ_actsb + SZ_enc + SZ_part;  // 193 MB
  const size_t baseC = SMALL + SZ_WdecT + SZ_actsb + SZ_enc;
  const size_t baseD = SMALL;
  if (ws_size >= baseA + 256 * ROWB_preb) {
    plan = 0;
    CH = (ws_size - baseA) / ROWB_preb;
    CH = (CH / 256) * 256;
  } else if (ws_size >= baseC + 128 * ROWB_pref) {
    plan = 1;
    CH = (ws_size - baseC) / ROWB_pref;
    CH = (CH / 128) * 128;
  } else if (ws_size >= baseD + 128 * (ROWB_pref + ROWB_enc)) {
    plan = 2;
    CH = (ws_size - baseD) / (ROWB_pref + ROWB_enc);
    CH = (CH / 128) * 128;
  } else {
    return;
  }
  if (CH > NROWS) CH = NROWS;

  size_t off = SMALL;
  bf16_t* WencT = nullptr; bf16_t* WdecT = nullptr; bf16_t* actsb = nullptr;
  bf16_t* enc = nullptr; bf16_t* encC = nullptr;
  float* part = nullptr; void* pre = nullptr;
  if (plan == 0) { WencT = (bf16_t*)(ws + off); off += SZ_WencT; }
  if (plan <= 1) {
    WdecT = (bf16_t*)(ws + off); off += SZ_WdecT;
    actsb = (bf16_t*)(ws + off); off += SZ_actsb;
    enc   = (bf16_t*)(ws + off); off += SZ_enc;
  }
  if (plan == 0) { part = (float*)(ws + off); off += SZ_part; }
  pre = (void*)(ws + off); off += CH * (plan == 0 ? ROWB_preb : ROWB_pref);
  if (plan == 2) { encC = (bf16_t*)(ws + off); off += CH * ROWB_enc; }

  col_norm_partial<<<dim3(64, 8), 256, 0, stream>>>(W_enc, colpart);
  col_norm_finalize<<<64, 256, 0, stream>>>(colpart, scale_enc);
  row_norm_kernel<<<NFEAT / 4, 256, 0, stream>>>(W_dec, scale_dec);

  if (plan == 0) {
    transpose_scale_cast<-1><<<dim3(D_SAE / 64, D_IN / 64), 256, 0, stream>>>(
        W_enc, nullptr, WencT, D_SAE, D_IN);
    transpose_scale_cast<-1><<<dim3(D_IN / 64, NFEAT / 64), 256, 0, stream>>>(
        W_dec, nullptr, WdecT, D_IN, NFEAT);
  } else if (plan == 1) {
    transpose_scale_cast<1><<<dim3(D_IN / 64, NFEAT / 64), 256, 0, stream>>>(
        W_dec, scale_dec, WdecT, D_IN, NFEAT);
  }
  if (plan <= 1)
    cast_bf16_kernel<<<(NROWS * D_IN / 4 + 255) / 256, 256, 0, stream>>>(
        acts, actsb, NROWS * D_IN / 4);

  for (size_t r0 = 0; r0 < NROWS; r0 += CH) {
    size_t Mi = NROWS - r0 < CH ? NROWS - r0 : CH;
    if (plan == 0) {
      gemm256p<true><<<dim3(D_SAE / 256, Mi / 256, 1), 512, 0, stream>>>(
          actsb + r0 * D_IN, WencT, pre, D_SAE, D_IN, D_IN, D_IN, 0);
      row_process<0><<<Mi, 256, 0, stream>>>(pre, scale_enc, b_enc, ln_w, ln_b,
                                             fmask, scale_dec, enc + r0 * NFEAT);
    } else if (plan == 1) {
      gemm_tile<0, 1><<<dim3(D_SAE / 128, Mi / 128), 256, 0, stream>>>(
          actsb + r0 * D_IN, W_enc, scale_enc, b_enc, (float*)pre, D_SAE, D_IN, D_IN, D_SAE);
      row_process<1><<<Mi, 256, 0, stream>>>(pre, nullptr, nullptr, ln_w, ln_b,
                                             fmask, nullptr, enc + r0 * NFEAT);
    } else {
      gemm_tile<1, 1><<<dim3(D_SAE / 128, Mi / 128), 256, 0, stream>>>(
          acts + r0 * D_IN, W_enc, scale_enc, b_enc, (float*)pre, D_SAE, D_IN, D_IN, D_SAE);
      row_process<1><<<Mi, 256, 0, stream>>>(pre, nullptr, nullptr, ln_w, ln_b,
                                             fmask, nullptr, encC);
      gemm_tile<0, 2><<<dim3(D_IN / 128, Mi / 128), 256, 0, stream>>>(
          encC, W_dec, scale_dec, b_dec, out + r0 * D_IN, D_IN, NFEAT, NFEAT, D_IN);
    }
  }
  if (plan == 0) {
    // GEMM2 split-K=2: 8x16x2 = 256 blocks (full machine), partials then combine
    gemm256p<false><<<dim3(D_IN / 256, NROWS / 256, 2), 512, 0, stream>>>(
        enc, WdecT, part, D_IN, NFEAT / 2, NFEAT, NFEAT, (size_t)NROWS * D_IN);
    combine_kernel<<<(NROWS * D_IN / 4 + 255) / 256, 256, 0, stream>>>(
        part, part + (size_t)NROWS * D_IN, b_dec, out, NROWS * D_IN / 4);
  } else if (plan == 1) {
    gemm_tile<0, 0><<<dim3(D_IN / 128, NROWS / 128), 256, 0, stream>>>(
        enc, WdecT, nullptr, b_dec, out, D_IN, NFEAT, NFEAT, NFEAT);
  }
}

// Round 6
// 591.449 us; speedup vs baseline: 1.1966x; 1.0836x over previous
//
#include <hip/hip_runtime.h>
#include <hip/hip_bf16.h>

typedef __bf16 bf16_t;
typedef __attribute__((ext_vector_type(8))) __bf16 bf16x8;
typedef __attribute__((ext_vector_type(4))) __bf16 bf16x4;
typedef __attribute__((ext_vector_type(4))) float f32x4;

#define D_IN   2048
#define D_SAE  16384
#define NROWS  4096
#define NFEAT  4096     // INIT_FEATURES (first NFEAT features unmasked; rest exactly zero)
#define TOPK   1638
#define W_EPS  1e-8f
#define LN_EPS 1e-5f
#define TEMP_INV 10.0f

// ---------------- reductions ----------------
__device__ inline float blockSumF(float v, float* red) {
#pragma unroll
  for (int o = 32; o; o >>= 1) v += __shfl_xor(v, o, 64);
  __syncthreads();
  if ((threadIdx.x & 63) == 0) red[threadIdx.x >> 6] = v;
  __syncthreads();
  return red[0] + red[1] + red[2] + red[3];
}

__device__ inline int blockSumI(int v, int* red) {
#pragma unroll
  for (int o = 32; o; o >>= 1) v += __shfl_xor(v, o, 64);
  __syncthreads();
  if ((threadIdx.x & 63) == 0) red[threadIdx.x >> 6] = v;
  __syncthreads();
  return red[0] + red[1] + red[2] + red[3];
}

// ---------------- W_enc column norms (plans 1/2 only: from f32 W_enc) ----------------
__global__ __launch_bounds__(256) void col_norm_partial(const float* __restrict__ W,
                                                        float* __restrict__ part) {
  int col = blockIdx.x * 256 + threadIdx.x;
  int rc = blockIdx.y;
  const float* p = W + (size_t)rc * 256 * D_SAE + col;
  float s = 0.f;
#pragma unroll 8
  for (int r = 0; r < 256; ++r) {
    float v = p[(size_t)r * D_SAE];
    s += v * v;
  }
  part[(size_t)rc * D_SAE + col] = s;
}

__global__ __launch_bounds__(256) void col_norm_finalize(const float* __restrict__ part,
                                                         float* __restrict__ scale) {
  int col = blockIdx.x * 256 + threadIdx.x;
  float s = 0.f;
#pragma unroll
  for (int c = 0; c < 8; ++c) s += part[(size_t)c * D_SAE + col];
  scale[col] = 1.0f / (sqrtf(s) + W_EPS);
}

// ---------------- plan 0: W_enc column norms from transposed bf16 copy ----------------
// One wave per WencT row (= W_enc column). 64 MB read vs 128 MB f32 re-read.
__global__ __launch_bounds__(256) void colnorm_from_T(const bf16_t* __restrict__ WT,
                                                      float* __restrict__ scale) {
  int row = (blockIdx.x * 256 + threadIdx.x) >> 6;
  int lane = threadIdx.x & 63;
  const bf16x8* r8 = (const bf16x8*)(WT + (size_t)row * D_IN);
  float s = 0.f;
#pragma unroll
  for (int i = 0; i < D_IN / 8 / 64; ++i) {  // 4 iters
    bf16x8 v = r8[lane + i * 64];
#pragma unroll
    for (int j = 0; j < 8; ++j) { float f = (float)v[j]; s += f * f; }
  }
#pragma unroll
  for (int o = 32; o; o >>= 1) s += __shfl_xor(s, o, 64);
  if (lane == 0) scale[row] = 1.0f / (sqrtf(s) + W_EPS);
}

// ---------------- W_dec row norms ----------------
__global__ __launch_bounds__(256) void row_norm_kernel(const float* __restrict__ W,
                                                       float* __restrict__ scale) {
  int gw = (blockIdx.x * 256 + threadIdx.x) >> 6;
  int lane = threadIdx.x & 63;
  const float4* r4 = (const float4*)(W + (size_t)gw * D_IN);
  float s = 0.f;
#pragma unroll
  for (int i = 0; i < (D_IN / 4) / 64; ++i) {
    float4 v = r4[lane + i * 64];
    s += v.x * v.x + v.y * v.y + v.z * v.z + v.w * v.w;
  }
#pragma unroll
  for (int o = 32; o; o >>= 1) s += __shfl_xor(s, o, 64);
  if (lane == 0) scale[gw] = 1.0f / (sqrtf(s) + W_EPS);
}

// ---------------- transpose (+optional scale) + cast to bf16 ----------------
template <int SCALE_AXIS>
__global__ __launch_bounds__(256) void transpose_scale_cast(
    const float* __restrict__ in, const float* __restrict__ scale,
    bf16_t* __restrict__ out, int C, int Rout) {
  __shared__ float t[64][65];
  int c0 = blockIdx.x * 64;
  int r0 = blockIdx.y * 64;
  int tx = threadIdx.x & 63;
  int ty = threadIdx.x >> 6;
#pragma unroll
  for (int i = 0; i < 16; ++i) {
    int r = ty * 16 + i;
    float v = in[(size_t)(r0 + r) * C + (c0 + tx)];
    float sc = (SCALE_AXIS == 0) ? scale[c0 + tx]
             : (SCALE_AXIS == 1) ? scale[r0 + r] : 1.0f;
    t[r][tx] = v * sc;
  }
  __syncthreads();
#pragma unroll
  for (int i = 0; i < 16; ++i) {
    int r = ty * 16 + i;
    out[(size_t)(c0 + r) * Rout + (r0 + tx)] = (bf16_t)t[tx][r];
  }
}

// ---------------- cast acts f32 -> bf16 ----------------
__global__ __launch_bounds__(256) void cast_bf16_kernel(const float* __restrict__ in,
                                                        bf16_t* __restrict__ out, int n4) {
  int i = blockIdx.x * 256 + threadIdx.x;
  if (i < n4) {
    float4 v = ((const float4*)in)[i];
    bf16x4 o;
    o[0] = (bf16_t)v.x; o[1] = (bf16_t)v.y; o[2] = (bf16_t)v.z; o[3] = (bf16_t)v.w;
    *(bf16x4*)(out + (size_t)i * 4) = o;
  }
}

// ---------------- combine: out = p0 + p1 + bias[col] ----------------
__global__ __launch_bounds__(256) void combine_kernel(const float* __restrict__ p0,
                                                      const float* __restrict__ p1,
                                                      const float* __restrict__ bias,
                                                      float* __restrict__ out, int n4) {
  int i = blockIdx.x * 256 + threadIdx.x;
  if (i < n4) {
    float4 a = ((const float4*)p0)[i];
    float4 b = ((const float4*)p1)[i];
    float4 c = ((const float4*)bias)[i & (D_IN / 4 - 1)];
    float4 o;
    o.x = a.x + b.x + c.x; o.y = a.y + b.y + c.y;
    o.z = a.z + b.z + c.z; o.w = a.w + b.w + c.w;
    ((float4*)out)[i] = o;
  }
}

__device__ inline void gload_lds16(const bf16_t* g, bf16_t* l) {
  __builtin_amdgcn_global_load_lds((__attribute__((address_space(1))) void*)g,
                                   (__attribute__((address_space(3))) void*)l,
                                   16, 0, 0);
}

// ============ 256x256 8-phase pipelined bf16 MFMA GEMM ============
// Race-free liveness-derived stage schedule: 1 half-tile stage per phase,
// each stage >=1 barrier after its region's last drained read; vmcnt(4) at
// P4/P8 tails drains exactly the tile needed 4 phases later.
// Cz = A[:, zK:(z+1)K] * BT[:, zK:(z+1)K]^T.  M%256==0, N%256==0, K%128==0.
template <bool BF16_OUT>
__global__ __launch_bounds__(512, 2) void gemm256p(
    const bf16_t* __restrict__ A, const bf16_t* __restrict__ BT,
    void* __restrict__ Cv, int N, int K, int lda, int ldb, size_t czstride) {
  __shared__ __align__(16) bf16_t As[2][2][128 * 64];
  __shared__ __align__(16) bf16_t Bs[2][2][128 * 64];

  const int tid = threadIdx.x;
  const int lane = tid & 63;
  const int w = tid >> 6;       // 0..7
  const int wm = w >> 2;        // 0..1
  const int wn = w & 3;         // 0..3

  const int z = blockIdx.z;
  A += (size_t)z * K;
  BT += (size_t)z * K;

  // XCD swizzle (bijective when nwg%8==0)
  const int gx = gridDim.x, gy = gridDim.y;
  const int nwg = gx * gy;
  int orig = blockIdx.y * gx + blockIdx.x;
  int wgid = orig;
  if ((nwg & 7) == 0) wgid = (orig & 7) * (nwg >> 3) + (orig >> 3);
  const int bx = wgid / gy;
  const int by = wgid % gy;
  const long brow = (long)by * 256;
  const long bcol = (long)bx * 256;

  // staging: per half-tile (128 rows x 64 k) each thread does 2 x 16B loads.
  const int srow = lane >> 3;                      // 0..7
  const int sg = ((lane & 7) ^ srow) * 8;          // swizzled granule (elems)
  const bf16_t* a0 = A + (size_t)(brow + w * 16 + srow) * lda + sg;
  const bf16_t* b0 = BT + (size_t)(bcol + w * 16 + srow) * ldb + sg;
  const int ldsb = w * 1024;                       // elem offset of wave's region

#define STAGE_A(p_, h_, kt_)                                                   \
  do {                                                                         \
    gload_lds16(a0 + (size_t)((h_)*128 + 0) * lda + (kt_), &As[p_][h_][ldsb]); \
    gload_lds16(a0 + (size_t)((h_)*128 + 8) * lda + (kt_), &As[p_][h_][ldsb + 512]); \
  } while (0)
#define STAGE_B(p_, h_, kt_)                                                   \
  do {                                                                         \
    gload_lds16(b0 + (size_t)((h_)*128 + 0) * ldb + (kt_), &Bs[p_][h_][ldsb]); \
    gload_lds16(b0 + (size_t)((h_)*128 + 8) * ldb + (kt_), &Bs[p_][h_][ldsb + 512]); \
  } while (0)

  // fragment read offsets (byte, within a half region; row r at byte 128r,
  // granule g at byte (g^(r&7))*16 — matches staging swizzle)
  const int fr = lane & 15;
  const int kq = (lane >> 4) * 16;
  const int xr = (fr & 7) << 4;
  const int aoffs0 = fr * 128 + (kq ^ xr);
  const int aoffs1 = fr * 128 + ((64 + kq) ^ xr);
  const int boffs0 = ((wn & 1) * 64 + fr) * 128 + (kq ^ xr);
  const int boffs1 = ((wn & 1) * 64 + fr) * 128 + ((64 + kq) ^ xr);

  bf16x8 aF[4][2], bF[4][2];
  f32x4 acc[8][4] = {};

#define RD_A(P_, MH_)                                                          \
  do {                                                                         \
    const char* aB_ = (const char*)&As[P_][wm][0] + (MH_)*8192;                \
    _Pragma("unroll") for (int m_ = 0; m_ < 4; ++m_) {                         \
      aF[m_][0] = *(const bf16x8*)(aB_ + m_ * 2048 + aoffs0);                  \
      aF[m_][1] = *(const bf16x8*)(aB_ + m_ * 2048 + aoffs1);                  \
    }                                                                          \
  } while (0)
#define RD_B(P_, N0_)                                                          \
  do {                                                                         \
    const char* bB_ = (const char*)&Bs[P_][wn >> 1][0];                        \
    _Pragma("unroll") for (int n_ = 0; n_ < 2; ++n_) {                         \
      bF[(N0_) + n_][0] = *(const bf16x8*)(bB_ + ((N0_) + n_) * 2048 + boffs0);\
      bF[(N0_) + n_][1] = *(const bf16x8*)(bB_ + ((N0_) + n_) * 2048 + boffs1);\
    }                                                                          \
  } while (0)
#define MFMA16(MH_, NP_)                                                       \
  do {                                                                         \
    _Pragma("unroll") for (int m_ = 0; m_ < 4; ++m_) {                         \
      _Pragma("unroll") for (int n_ = 0; n_ < 2; ++n_) {                       \
        acc[(MH_)*4 + m_][(NP_)*2 + n_] = __builtin_amdgcn_mfma_f32_16x16x32_bf16( \
            aF[m_][0], bF[(NP_)*2 + n_][0], acc[(MH_)*4 + m_][(NP_)*2 + n_], 0, 0, 0); \
        acc[(MH_)*4 + m_][(NP_)*2 + n_] = __builtin_amdgcn_mfma_f32_16x16x32_bf16( \
            aF[m_][1], bF[(NP_)*2 + n_][1], acc[(MH_)*4 + m_][(NP_)*2 + n_], 0, 0, 0); \
      }                                                                        \
    }                                                                          \
  } while (0)

#define VM4 asm volatile("s_waitcnt vmcnt(4)" ::: "memory")
#define VM0 asm volatile("s_waitcnt vmcnt(0)" ::: "memory")
#define LGKM8 asm volatile("s_waitcnt lgkmcnt(8)" ::: "memory")
#define NOPX (void)0

#define PHASE(RDS, STG, HINT, TAIL, MH_, NP_)                                  \
  do {                                                                         \
    RDS;                                                                       \
    STG;                                                                       \
    HINT;                                                                      \
    __builtin_amdgcn_s_barrier();                                              \
    asm volatile("s_waitcnt lgkmcnt(0)" ::: "memory");                         \
    __builtin_amdgcn_s_setprio(1);                                             \
    MFMA16(MH_, NP_);                                                          \
    __builtin_amdgcn_s_setprio(0);                                             \
    TAIL;                                                                      \
    __builtin_amdgcn_s_barrier();                                              \
  } while (0)

  const int NITER = K >> 7;   // 2 K-tiles (BK=64) per iteration

  // prologue: tile0 full (buf0) + tile1 B halves (buf1) = 12 loads
  STAGE_B(0, 0, 0); STAGE_B(0, 1, 0); STAGE_A(0, 0, 0); STAGE_A(0, 1, 0);
  STAGE_B(1, 0, 64); STAGE_B(1, 1, 64);
  VM4;                                  // oldest 8 = all of tile0 landed
  __builtin_amdgcn_s_barrier();

  for (int it = 0; it < NITER - 1; ++it) {
    const int kt = it * 128;
    // tiles 2it (buf0), 2it+1 (buf1); stage A(2it+1)@P1-2, tile 2it+2 @P3-6,
    // B(2it+3)@P7-8.  VM4@P4 drains through P2; VM4@P8 drains through P6.
    PHASE(RD_A(0, 0); RD_B(0, 0), STAGE_A(1, 0, kt + 64),  LGKM8, NOPX, 0, 0);
    PHASE(RD_B(0, 2),             STAGE_A(1, 1, kt + 64),  NOPX,  NOPX, 0, 1);
    PHASE(RD_A(0, 1),             STAGE_B(0, 0, kt + 128), NOPX,  NOPX, 1, 0);
    PHASE(NOPX,                   STAGE_B(0, 1, kt + 128), NOPX,  VM4,  1, 1);
    PHASE(RD_A(1, 0); RD_B(1, 0), STAGE_A(0, 0, kt + 128), LGKM8, NOPX, 0, 0);
    PHASE(RD_B(1, 2),             STAGE_A(0, 1, kt + 128), NOPX,  NOPX, 0, 1);
    PHASE(RD_A(1, 1),             STAGE_B(1, 0, kt + 192), NOPX,  NOPX, 1, 0);
    PHASE(NOPX,                   STAGE_B(1, 1, kt + 192), NOPX,  VM4,  1, 1);
  }
  {
    const int kt = (NITER - 1) * 128;   // last pair: tiles NT-2, NT-1
    PHASE(RD_A(0, 0); RD_B(0, 0), STAGE_A(1, 0, kt + 64), LGKM8, NOPX, 0, 0);
    PHASE(RD_B(0, 2),             STAGE_A(1, 1, kt + 64), NOPX,  NOPX, 0, 1);
    PHASE(RD_A(0, 1),             NOPX, NOPX, NOPX, 1, 0);
    PHASE(NOPX,                   NOPX, NOPX, VM0,  1, 1);   // drain all
    PHASE(RD_A(1, 0); RD_B(1, 0), NOPX, LGKM8, NOPX, 0, 0);
    PHASE(RD_B(1, 2),             NOPX, NOPX, NOPX, 0, 1);
    PHASE(RD_A(1, 1),             NOPX, NOPX, NOPX, 1, 0);
    PHASE(NOPX,                   NOPX, NOPX, NOPX, 1, 1);
  }
#undef PHASE
#undef STAGE_A
#undef STAGE_B

  // ---- epilogue ----
#pragma unroll
  for (int m = 0; m < 8; ++m) {
#pragma unroll
    for (int r = 0; r < 4; ++r) {
      size_t row = brow + wm * 128 + m * 16 + (lane >> 4) * 4 + r;
      if (BF16_OUT) {
        bf16_t* cp = (bf16_t*)Cv + row * (size_t)N + bcol + wn * 64 + fr;
#pragma unroll
        for (int n = 0; n < 4; ++n) cp[n * 16] = (bf16_t)acc[m][n][r];
      } else {
        float* cp = (float*)Cv + z * czstride + row * (size_t)N + bcol + wn * 64 + fr;
#pragma unroll
        for (int n = 0; n < 4; ++n) cp[n * 16] = acc[m][n][r];
      }
    }
  }
}

// ---------------- unified 128x128 MFMA GEMM (fallback plans) ----------------
template <int AMODE, int BMODE>
__global__ __launch_bounds__(256, 2) void gemm_tile(
    const void* __restrict__ Ap, const void* __restrict__ Bp,
    const float* __restrict__ bscale, const float* __restrict__ bias,
    float* __restrict__ C, int N, int K, int lda, int ldb) {
  __shared__ __align__(16) bf16_t As[128 * 32];
  __shared__ __align__(16) bf16_t Bs[128 * 32];
  const int tid = threadIdx.x;
  const int lane = tid & 63;
  const int wid = tid >> 6;
  const int wm = wid >> 1, wn = wid & 1;
  const long brow = (long)blockIdx.y * 128;
  const long bcol = (long)blockIdx.x * 128;

  f32x4 acc[4][4] = {};

  const bf16_t* ag = nullptr; bf16_t* al = nullptr;
  const float* af32 = nullptr;
  if (AMODE == 0) {
    ag = (const bf16_t*)Ap + (size_t)(brow + wid * 32 + (lane >> 2)) * lda + (lane & 3) * 8;
    al = &As[(wid * 32) * 32];
  } else {
    af32 = (const float*)Ap;
  }
  const bf16_t* bg = nullptr; bf16_t* bl = nullptr;
  const float* bf32 = nullptr;
  if (BMODE == 0) {
    bg = (const bf16_t*)Bp + (size_t)(bcol + wid * 32 + (lane >> 2)) * ldb + (lane & 3) * 8;
    bl = &Bs[(wid * 32) * 32];
  } else {
    bf32 = (const float*)Bp;
  }

  const int fr = lane & 15;
  const int kc = (lane >> 4) * 8;
  const int aoff0 = (wm * 64 + fr) * 32 + kc;
  const int boff0 = (wn * 64 + fr) * 32 + kc;

  for (int kt = 0; kt < K; kt += 32) {
    if (AMODE == 0) {
      gload_lds16(ag + kt, al);
      gload_lds16(ag + kt + (size_t)16 * lda, al + 16 * 32);
    } else {
#pragma unroll
      for (int i = 0; i < 4; ++i) {
        int flat = tid + i * 256;
        int r = flat >> 3;
        int k4 = flat & 7;
        float4 v = *(const float4*)&af32[(size_t)(brow + r) * lda + kt + k4 * 4];
        bf16x4 o;
        o[0] = (bf16_t)v.x; o[1] = (bf16_t)v.y; o[2] = (bf16_t)v.z; o[3] = (bf16_t)v.w;
        *(bf16x4*)&As[r * 32 + k4 * 4] = o;
      }
    }
    if (BMODE == 0) {
      gload_lds16(bg + kt, bl);
      gload_lds16(bg + kt + (size_t)16 * ldb, bl + 16 * 32);
    } else {
#pragma unroll
      for (int i = 0; i < 4; ++i) {
        int flat = tid + i * 256;
        int k = flat >> 5;
        int c4 = flat & 31;
        float4 v = *(const float4*)&bf32[(size_t)(kt + k) * ldb + bcol + c4 * 4];
        float4 sc;
        if (BMODE == 1) {
          sc = *(const float4*)&bscale[bcol + c4 * 4];
        } else {
          float s = bscale[kt + k];
          sc.x = s; sc.y = s; sc.z = s; sc.w = s;
        }
        Bs[(c4 * 4 + 0) * 32 + k] = (bf16_t)(v.x * sc.x);
        Bs[(c4 * 4 + 1) * 32 + k] = (bf16_t)(v.y * sc.y);
        Bs[(c4 * 4 + 2) * 32 + k] = (bf16_t)(v.z * sc.z);
        Bs[(c4 * 4 + 3) * 32 + k] = (bf16_t)(v.w * sc.w);
      }
    }
    __syncthreads();
    bf16x8 afr[4], bfr[4];
#pragma unroll
    for (int m = 0; m < 4; ++m) afr[m] = *(const bf16x8*)&As[aoff0 + m * 16 * 32];
#pragma unroll
    for (int n = 0; n < 4; ++n) bfr[n] = *(const bf16x8*)&Bs[boff0 + n * 16 * 32];
#pragma unroll
    for (int m = 0; m < 4; ++m)
#pragma unroll
      for (int n = 0; n < 4; ++n)
        acc[m][n] = __builtin_amdgcn_mfma_f32_16x16x32_bf16(afr[m], bfr[n], acc[m][n], 0, 0, 0);
    __syncthreads();
  }

  float bval[4];
#pragma unroll
  for (int n = 0; n < 4; ++n) bval[n] = bias ? bias[bcol + wn * 64 + n * 16 + fr] : 0.0f;
#pragma unroll
  for (int m = 0; m < 4; ++m) {
#pragma unroll
    for (int r = 0; r < 4; ++r) {
      size_t row = brow + wm * 64 + m * 16 + (lane >> 4) * 4 + r;
      float* cp = C + row * (size_t)N + bcol + wn * 64 + fr;
#pragma unroll
      for (int n = 0; n < 4; ++n) cp[n * 16] = acc[m][n][r] + bval[n];
    }
  }
}

// ---------------- per-row: (scale+bias) -> LN -> affine -> LN -> topK -> encoded ----------------
template <int MODE>
__global__ __launch_bounds__(256) void row_process(
    const void* __restrict__ prev, const float* __restrict__ senc,
    const float* __restrict__ b_enc, const float* __restrict__ ln_w,
    const float* __restrict__ ln_b, const float* __restrict__ fmask,
    const float* __restrict__ sdec, bf16_t* __restrict__ enc_base) {
  __shared__ float redf[4];
  __shared__ int redi[4];
  const int tid = threadIdx.x;
  const size_t row = blockIdx.x;

  float4 x[16];
  float s = 0.f, s2 = 0.f;
  if (MODE == 0) {
    const bf16x8* xr = (const bf16x8*)((const bf16_t*)prev + row * D_SAE);
    const float4* s4 = (const float4*)senc;
    const float4* b4 = (const float4*)b_enc;
#pragma unroll
    for (int jj = 0; jj < 8; ++jj) {
      bf16x8 v = xr[tid + jj * 256];
      int i4 = (tid + jj * 256) * 2;
      float4 sa = s4[i4], sb = s4[i4 + 1];
      float4 ba = b4[i4], bb = b4[i4 + 1];
      float4 lo, hi;
      lo.x = (float)v[0] * sa.x + ba.x;
      lo.y = (float)v[1] * sa.y + ba.y;
      lo.z = (float)v[2] * sa.z + ba.z;
      lo.w = (float)v[3] * sa.w + ba.w;
      hi.x = (float)v[4] * sb.x + bb.x;
      hi.y = (float)v[5] * sb.y + bb.y;
      hi.z = (float)v[6] * sb.z + bb.z;
      hi.w = (float)v[7] * sb.w + bb.w;
      x[2 * jj] = lo; x[2 * jj + 1] = hi;
      s += lo.x + lo.y + lo.z + lo.w + hi.x + hi.y + hi.z + hi.w;
      s2 += lo.x * lo.x + lo.y * lo.y + lo.z * lo.z + lo.w * lo.w +
            hi.x * hi.x + hi.y * hi.y + hi.z * hi.z + hi.w * hi.w;
    }
  } else {
    const float4* xr = (const float4*)((const float*)prev + row * D_SAE);
#pragma unroll
    for (int j = 0; j < 16; ++j) {
      float4 v = xr[tid + j * 256];
      x[j] = v;
      s += v.x + v.y + v.z + v.w;
      s2 += v.x * v.x + v.y * v.y + v.z * v.z + v.w * v.w;
    }
  }
  float S1 = blockSumF(s, redf);
  float S2 = blockSumF(s2, redf);
  float mu = S1 * (1.0f / D_SAE);
  float var = S2 * (1.0f / D_SAE) - mu * mu;
  float inv = rsqrtf(var + LN_EPS);

#define IDX4(j) ((MODE == 0) ? ((tid + ((j) >> 1) * 256) * 2 + ((j) & 1)) : (tid + (j) * 256))
  const float4* wr = (const float4*)ln_w;
  const float4* br = (const float4*)ln_b;
  s = 0.f; s2 = 0.f;
#pragma unroll
  for (int j = 0; j < 16; ++j) {
    float4 ww = wr[IDX4(j)];
    float4 bb = br[IDX4(j)];
    float4 h;
    h.x = (x[j].x - mu) * inv * ww.x + bb.x;
    h.y = (x[j].y - mu) * inv * ww.y + bb.y;
    h.z = (x[j].z - mu) * inv * ww.z + bb.z;
    h.w = (x[j].w - mu) * inv * ww.w + bb.w;
    x[j] = h;
    s += h.x + h.y + h.z + h.w;
    s2 += h.x * h.x + h.y * h.y + h.z * h.z + h.w * h.w;
  }
  float T1 = blockSumF(s, redf);
  float T2 = blockSumF(s2, redf);
  float mu2 = T1 * (1.0f / D_SAE);
  float inv2 = rsqrtf(T2 * (1.0f / D_SAE) - mu2 * mu2 + LN_EPS);
#pragma unroll
  for (int j = 0; j < 16; ++j) {
    x[j].x = (x[j].x - mu2) * inv2;
    x[j].y = (x[j].y - mu2) * inv2;
    x[j].z = (x[j].z - mu2) * inv2;
    x[j].w = (x[j].w - mu2) * inv2;
  }

  unsigned ans = 0u;
  for (int bit = 31; bit >= 0; --bit) {
    unsigned u = ans | (1u << bit);
    unsigned bb = (u & 0x80000000u) ? (u ^ 0x80000000u) : ~u;
    float tc = __uint_as_float(bb);
    int c = 0;
#pragma unroll
    for (int j = 0; j < 16; ++j) {
      c += (x[j].x >= tc) ? 1 : 0;
      c += (x[j].y >= tc) ? 1 : 0;
      c += (x[j].z >= tc) ? 1 : 0;
      c += (x[j].w >= tc) ? 1 : 0;
    }
    c = blockSumI(c, redi);
    if (c >= TOPK) ans = u;
  }
  unsigned tb = (ans & 0x80000000u) ? (ans ^ 0x80000000u) : ~ans;
  float thr = __uint_as_float(tb);

  const float4* mr = (const float4*)fmask;
  if (MODE == 0) {
    const float4* d4 = (const float4*)sdec;
#pragma unroll
    for (int jj = 0; jj < 2; ++jj) {
      int i4 = (tid + jj * 256) * 2;
      float4 m0 = mr[i4], m1 = mr[i4 + 1];
      float4 d0 = d4[i4], d1 = d4[i4 + 1];
      float4 a = x[2 * jj], b = x[2 * jj + 1];
      bf16x8 o;
      o[0] = (bf16_t)(a.x * m0.x / (1.0f + __expf((thr - a.x) * TEMP_INV)) * d0.x);
      o[1] = (bf16_t)(a.y * m0.y / (1.0f + __expf((thr - a.y) * TEMP_INV)) * d0.y);
      o[2] = (bf16_t)(a.z * m0.z / (1.0f + __expf((thr - a.z) * TEMP_INV)) * d0.z);
      o[3] = (bf16_t)(a.w * m0.w / (1.0f + __expf((thr - a.w) * TEMP_INV)) * d0.w);
      o[4] = (bf16_t)(b.x * m1.x / (1.0f + __expf((thr - b.x) * TEMP_INV)) * d1.x);
      o[5] = (bf16_t)(b.y * m1.y / (1.0f + __expf((thr - b.y) * TEMP_INV)) * d1.y);
      o[6] = (bf16_t)(b.z * m1.z / (1.0f + __expf((thr - b.z) * TEMP_INV)) * d1.z);
      o[7] = (bf16_t)(b.w * m1.w / (1.0f + __expf((thr - b.w) * TEMP_INV)) * d1.w);
      ((bf16x8*)(enc_base + row * NFEAT))[tid + jj * 256] = o;
    }
  } else {
#pragma unroll
    for (int j = 0; j < NFEAT / 1024; ++j) {
      float4 m = mr[tid + j * 256];
      float4 h = x[j];
      float4 e;
      e.x = h.x * m.x / (1.0f + __expf((thr - h.x) * TEMP_INV));
      e.y = h.y * m.y / (1.0f + __expf((thr - h.y) * TEMP_INV));
      e.z = h.z * m.z / (1.0f + __expf((thr - h.z) * TEMP_INV));
      e.w = h.w * m.w / (1.0f + __expf((thr - h.w) * TEMP_INV));
      bf16x4 o;
      o[0] = (bf16_t)e.x; o[1] = (bf16_t)e.y; o[2] = (bf16_t)e.z; o[3] = (bf16_t)e.w;
      *(bf16x4*)(enc_base + row * NFEAT + (size_t)(tid + j * 256) * 4) = o;
    }
  }
#undef IDX4
}

// ---------------- launch ----------------
extern "C" void kernel_launch(void* const* d_in, const int* in_sizes, int n_in,
                              void* d_out, int out_size, void* d_ws, size_t ws_size,
                              hipStream_t stream) {
  const float* acts  = (const float*)d_in[0];
  const float* W_enc = (const float*)d_in[1];
  const float* W_dec = (const float*)d_in[2];
  const float* b_enc = (const float*)d_in[3];
  const float* b_dec = (const float*)d_in[4];
  const float* ln_w  = (const float*)d_in[5];
  const float* ln_b  = (const float*)d_in[6];
  const float* fmask = (const float*)d_in[7];
  float* out = (float*)d_out;
  char* ws = (char*)d_ws;

  const size_t MB = 1u << 20;
  const size_t SMALL = MB;
  const size_t SZ_WencT = (size_t)D_SAE * D_IN * 2;     // 64 MB
  const size_t SZ_WdecT = (size_t)D_IN * NFEAT * 2;     // 16 MB
  const size_t SZ_actsb = (size_t)NROWS * D_IN * 2;     // 16 MB
  const size_t SZ_enc   = (size_t)NROWS * NFEAT * 2;    // 32 MB
  const size_t SZ_part  = (size_t)NROWS * D_IN * 4 * 2; // 64 MB
  const size_t ROWB_preb = (size_t)D_SAE * 2;
  const size_t ROWB_pref = (size_t)D_SAE * 4;
  const size_t ROWB_enc  = (size_t)NFEAT * 2;

  float* scale_enc = (float*)(ws + 0);
  float* scale_dec = (float*)(ws + 64 * 1024);
  float* colpart   = (float*)(ws + 128 * 1024);

  int plan;
  size_t CH;
  const size_t baseA = SMALL + SZ_WencT + SZ_WdecT + SZ_actsb + SZ_enc + SZ_part;
  const size_t baseC = SMALL + SZ_WdecT + SZ_actsb + SZ_enc;
  const size_t baseD = SMALL;
  if (ws_size >= baseA + 256 * ROWB_preb) {
    plan = 0;
    CH = (ws_size - baseA) / ROWB_preb;
    CH = (CH / 256) * 256;
  } else if (ws_size >= baseC + 128 * ROWB_pref) {
    plan = 1;
    CH = (ws_size - baseC) / ROWB_pref;
    CH = (CH / 128) * 128;
  } else if (ws_size >= baseD + 128 * (ROWB_pref + ROWB_enc)) {
    plan = 2;
    CH = (ws_size - baseD) / (ROWB_pref + ROWB_enc);
    CH = (CH / 128) * 128;
  } else {
    return;
  }
  if (CH > NROWS) CH = NROWS;

  size_t off = SMALL;
  bf16_t* WencT = nullptr; bf16_t* WdecT = nullptr; bf16_t* actsb = nullptr;
  bf16_t* enc = nullptr; bf16_t* encC = nullptr;
  float* part = nullptr; void* pre = nullptr;
  if (plan == 0) { WencT = (bf16_t*)(ws + off); off += SZ_WencT; }
  if (plan <= 1) {
    WdecT = (bf16_t*)(ws + off); off += SZ_WdecT;
    actsb = (bf16_t*)(ws + off); off += SZ_actsb;
    enc   = (bf16_t*)(ws + off); off += SZ_enc;
  }
  if (plan == 0) { part = (float*)(ws + off); off += SZ_part; }
  pre = (void*)(ws + off); off += CH * (plan == 0 ? ROWB_preb : ROWB_pref);
  if (plan == 2) { encC = (bf16_t*)(ws + off); off += CH * ROWB_enc; }

  if (plan == 0) {
    // transpose first; column norms from the bf16 transposed copy (saves a
    // full 128 MB f32 re-read; rel err ~1e-4 on the norm, negligible)
    transpose_scale_cast<-1><<<dim3(D_SAE / 64, D_IN / 64), 256, 0, stream>>>(
        W_enc, nullptr, WencT, D_SAE, D_IN);
    colnorm_from_T<<<D_SAE / 4, 256, 0, stream>>>(WencT, scale_enc);
    transpose_scale_cast<-1><<<dim3(D_IN / 64, NFEAT / 64), 256, 0, stream>>>(
        W_dec, nullptr, WdecT, D_IN, NFEAT);
  } else {
    col_norm_partial<<<dim3(64, 8), 256, 0, stream>>>(W_enc, colpart);
    col_norm_finalize<<<64, 256, 0, stream>>>(colpart, scale_enc);
    if (plan == 1)
      transpose_scale_cast<1><<<dim3(D_IN / 64, NFEAT / 64), 256, 0, stream>>>(
          W_dec, scale_dec, WdecT, D_IN, NFEAT);
  }
  row_norm_kernel<<<NFEAT / 4, 256, 0, stream>>>(W_dec, scale_dec);
  if (plan <= 1)
    cast_bf16_kernel<<<(NROWS * D_IN / 4 + 255) / 256, 256, 0, stream>>>(
        acts, actsb, NROWS * D_IN / 4);

  for (size_t r0 = 0; r0 < NROWS; r0 += CH) {
    size_t Mi = NROWS - r0 < CH ? NROWS - r0 : CH;
    if (plan == 0) {
      gemm256p<true><<<dim3(D_SAE / 256, Mi / 256, 1), 512, 0, stream>>>(
          actsb + r0 * D_IN, WencT, pre, D_SAE, D_IN, D_IN, D_IN, 0);
      row_process<0><<<Mi, 256, 0, stream>>>(pre, scale_enc, b_enc, ln_w, ln_b,
                                             fmask, scale_dec, enc + r0 * NFEAT);
    } else if (plan == 1) {
      gemm_tile<0, 1><<<dim3(D_SAE / 128, Mi / 128), 256, 0, stream>>>(
          actsb + r0 * D_IN, W_enc, scale_enc, b_enc, (float*)pre, D_SAE, D_IN, D_IN, D_SAE);
      row_process<1><<<Mi, 256, 0, stream>>>(pre, nullptr, nullptr, ln_w, ln_b,
                                             fmask, nullptr, enc + r0 * NFEAT);
    } else {
      gemm_tile<1, 1><<<dim3(D_SAE / 128, Mi / 128), 256, 0, stream>>>(
          acts + r0 * D_IN, W_enc, scale_enc, b_enc, (float*)pre, D_SAE, D_IN, D_IN, D_SAE);
      row_process<1><<<Mi, 256, 0, stream>>>(pre, nullptr, nullptr, ln_w, ln_b,
                                             fmask, nullptr, encC);
      gemm_tile<0, 2><<<dim3(D_IN / 128, Mi / 128), 256, 0, stream>>>(
          encC, W_dec, scale_dec, b_dec, out + r0 * D_IN, D_IN, NFEAT, NFEAT, D_IN);
    }
  }
  if (plan == 0) {
    gemm256p<false><<<dim3(D_IN / 256, NROWS / 256, 2), 512, 0, stream>>>(
        enc, WdecT, part, D_IN, NFEAT / 2, NFEAT, NFEAT, (size_t)NROWS * D_IN);
    combine_kernel<<<(NROWS * D_IN / 4 + 255) / 256, 256, 0, stream>>>(
        part, part + (size_t)NROWS * D_IN, b_dec, out, NROWS * D_IN / 4);
  } else if (plan == 1) {
    gemm_tile<0, 0><<<dim3(D_IN / 128, NROWS / 128), 256, 0, stream>>>(
        enc, WdecT, nullptr, b_dec, out, D_IN, NFEAT, NFEAT, NFEAT);
  }
}